// Round 5
// baseline (730.453 us; speedup 1.0000x reference)
//
#include <hip/hip_runtime.h>
#include <hip/hip_bf16.h>
#include <cstdint>
#include <cstddef>

#define NU      100000
#define NN      150000
#define DDIM    64
#define NNZ_C   2400000
#define B_C     4096
#define HIST_C  50
#define UHIST_C 30
#define MC_C    5
#define CDIM    192
#define IDIM    384
#define SCAN_B  147
#define SCAN_N  (SCAN_B * 1024)   // 150528 >= NN, padded for scan
#define MAXF    94208             // frontier slots (expected ~90.9K, sigma ~190 -> 17 sigma headroom)

// ---------------------------------------------------------------- CSR build
__global__ __launch_bounds__(256) void deg_kernel(
    const int* __restrict__ rows, int* __restrict__ deg) {
  int e = blockIdx.x * 256 + threadIdx.x;
  if (e < NNZ_C) atomicAdd(&deg[rows[e]], 1);
}

__global__ __launch_bounds__(1024) void scan_reduce(
    const int* __restrict__ deg, int* __restrict__ bsums) {
  __shared__ int s[1024];
  int t = threadIdx.x;
  s[t] = deg[blockIdx.x * 1024 + t];
  __syncthreads();
  for (int off = 512; off; off >>= 1) {
    if (t < off) s[t] += s[t + off];
    __syncthreads();
  }
  if (t == 0) bsums[blockIdx.x] = s[0];
}

// fused: in-block prefix over bsums + local scan; writes row_ptr AND fillp
__global__ __launch_bounds__(1024) void scan_final(
    const int* __restrict__ deg, const int* __restrict__ bsums,
    int* __restrict__ row_ptr, int* __restrict__ fillp) {
  __shared__ int pre[1024];
  __shared__ int s[1024];
  int t = threadIdx.x;
  pre[t] = (t < (int)blockIdx.x) ? bsums[t] : 0;  // blockIdx.x < SCAN_B <= 1024
  __syncthreads();
  for (int off = 512; off; off >>= 1) {
    if (t < off) pre[t] += pre[t + off];
    __syncthreads();
  }
  int base = pre[0];
  __syncthreads();
  int i = blockIdx.x * 1024 + t;
  int v = deg[i];
  s[t] = v;
  __syncthreads();
  for (int off = 1; off < 1024; off <<= 1) {
    int u = (t >= off) ? s[t - off] : 0;
    __syncthreads();
    s[t] += u;
    __syncthreads();
  }
  int rp = base + s[t] - v;  // exclusive
  row_ptr[i] = rp;
  if (i < NN) fillp[i] = rp;
  if (i == SCAN_N - 1) row_ptr[SCAN_N] = base + s[t];
}

__global__ __launch_bounds__(256) void csr_fill(
    const int* __restrict__ rows, const int* __restrict__ cols,
    const float* __restrict__ vals, int* __restrict__ fillp,
    int2* __restrict__ edges) {
  int e = blockIdx.x * 256 + threadIdx.x;
  if (e >= NNZ_C) return;
  int r = rows[e];
  int pos = atomicAdd(&fillp[r], 1);
  edges[pos] = make_int2(cols[e], __float_as_int(vals[e]));
}

// ---------------------------------------------------------------- frontier mark/compact
__global__ __launch_bounds__(256) void mark_kernel(
    const int* __restrict__ users, const int* __restrict__ items,
    const int* __restrict__ row_ptr, const int2* __restrict__ edges,
    int* __restrict__ flag) {
  int t = blockIdx.x * 256 + threadIdx.x;
  if (t >= 2 * B_C) return;
  int s = (t < B_C) ? users[t] : items[t - B_C] + NU;
  flag[s] = 1;
  int j0 = row_ptr[s], j1 = row_ptr[s + 1];
  for (int j = j0; j < j1; ++j) flag[edges[j].x] = 1;
}

__global__ __launch_bounds__(256) void compact_kernel(
    int* __restrict__ flag, int* __restrict__ list, int* __restrict__ cnt) {
  int n = blockIdx.x * 256 + threadIdx.x;
  if (n >= NN) return;
  if (flag[n]) {
    int i = atomicAdd(cnt, 1);
    if (i < MAXF) { list[i] = n; flag[n] = i + 1; }
    else flag[n] = 0;
  }
}

// ---------------------------------------------------------------- layer-1 gather SpMM
// 4 rows/wave, 16 lanes x float4 per row, unroll x2 -> 8 gather chains/wave
__global__ __launch_bounds__(256) void spmm_gather4(
    const float* __restrict__ src, float* __restrict__ dst,
    const int* __restrict__ row_ptr, const int2* __restrict__ edges) {
  int tid = threadIdx.x;
  int wave = tid >> 6, w = tid & 63, g = w >> 4, li = w & 15;
  int r = blockIdx.x * 16 + wave * 4 + g;
  int j0 = row_ptr[r], j1 = row_ptr[r + 1];
  float4 a0 = {0.f, 0.f, 0.f, 0.f}, a1 = {0.f, 0.f, 0.f, 0.f};
  int j = j0;
  for (; j + 2 <= j1; j += 2) {
    int2 e0 = edges[j], e1 = edges[j + 1];
    const float4 s0 = *(const float4*)(src + (size_t)e0.x * DDIM + li * 4);
    const float4 s1 = *(const float4*)(src + (size_t)e1.x * DDIM + li * 4);
    float v0 = __int_as_float(e0.y), v1 = __int_as_float(e1.y);
    a0.x += v0 * s0.x; a0.y += v0 * s0.y; a0.z += v0 * s0.z; a0.w += v0 * s0.w;
    a1.x += v1 * s1.x; a1.y += v1 * s1.y; a1.z += v1 * s1.z; a1.w += v1 * s1.w;
  }
  if (j < j1) {
    int2 e0 = edges[j];
    const float4 s0 = *(const float4*)(src + (size_t)e0.x * DDIM + li * 4);
    float v0 = __int_as_float(e0.y);
    a0.x += v0 * s0.x; a0.y += v0 * s0.y; a0.z += v0 * s0.z; a0.w += v0 * s0.w;
  }
  float4 o = {a0.x + a1.x, a0.y + a1.y, a0.z + a1.z, a0.w + a1.w};
  *(float4*)(dst + (size_t)r * DDIM + li * 4) = o;
}

// ---------------------------------------------------------------- masked layer-2 (compacted output)
__global__ __launch_bounds__(256) void spmm_gather4_masked(
    const float* __restrict__ src, float* __restrict__ dstc,
    const int* __restrict__ row_ptr, const int2* __restrict__ edges,
    const int* __restrict__ list, const int* __restrict__ cnt) {
  int tid = threadIdx.x;
  int wave = tid >> 6, w = tid & 63, g = w >> 4, li = w & 15;
  int p = blockIdx.x * 16 + wave * 4 + g;
  if (p >= cnt[0]) return;
  int r = list[p];
  int j0 = row_ptr[r], j1 = row_ptr[r + 1];
  float4 a0 = {0.f, 0.f, 0.f, 0.f}, a1 = {0.f, 0.f, 0.f, 0.f};
  int j = j0;
  for (; j + 2 <= j1; j += 2) {
    int2 e0 = edges[j], e1 = edges[j + 1];
    const float4 s0 = *(const float4*)(src + (size_t)e0.x * DDIM + li * 4);
    const float4 s1 = *(const float4*)(src + (size_t)e1.x * DDIM + li * 4);
    float v0 = __int_as_float(e0.y), v1 = __int_as_float(e1.y);
    a0.x += v0 * s0.x; a0.y += v0 * s0.y; a0.z += v0 * s0.z; a0.w += v0 * s0.w;
    a1.x += v1 * s1.x; a1.y += v1 * s1.y; a1.z += v1 * s1.z; a1.w += v1 * s1.w;
  }
  if (j < j1) {
    int2 e0 = edges[j];
    const float4 s0 = *(const float4*)(src + (size_t)e0.x * DDIM + li * 4);
    float v0 = __int_as_float(e0.y);
    a0.x += v0 * s0.x; a0.y += v0 * s0.y; a0.z += v0 * s0.z; a0.w += v0 * s0.w;
  }
  float4 o = {a0.x + a1.x, a0.y + a1.y, a0.z + a1.z, a0.w + a1.w};
  *(float4*)(dstc + (size_t)p * DDIM + li * 4) = o;
}

// ---------------------------------------------------------------- seed finish: g=(e0+e1+e2+e3)/4 -> uf/itf col 0
__global__ __launch_bounds__(256) void seed_finish(
    const float* __restrict__ emb, const float* __restrict__ e1,
    const float* __restrict__ e2c, const int* __restrict__ flag,
    const int* __restrict__ row_ptr, const int2* __restrict__ edges,
    const int* __restrict__ users, const int* __restrict__ items,
    float* __restrict__ uf, float* __restrict__ itf) {
  int tid = threadIdx.x;
  int wave = tid >> 6, w = tid & 63, g = w >> 4, li = w & 15;
  int qi = blockIdx.x * 16 + wave * 4 + g;
  int s = (qi < B_C) ? users[qi] : items[qi - B_C] + NU;
  int j0 = row_ptr[s], j1 = row_ptr[s + 1];
  float4 a0 = {0.f, 0.f, 0.f, 0.f}, a1 = {0.f, 0.f, 0.f, 0.f};
  int j = j0;
  for (; j + 2 <= j1; j += 2) {
    int2 e0 = edges[j], e1v = edges[j + 1];
    int p0 = flag[e0.x] - 1, p1 = flag[e1v.x] - 1;
    const float4 s0 = *(const float4*)(e2c + (size_t)p0 * DDIM + li * 4);
    const float4 s1 = *(const float4*)(e2c + (size_t)p1 * DDIM + li * 4);
    float v0 = __int_as_float(e0.y), v1 = __int_as_float(e1v.y);
    a0.x += v0 * s0.x; a0.y += v0 * s0.y; a0.z += v0 * s0.z; a0.w += v0 * s0.w;
    a1.x += v1 * s1.x; a1.y += v1 * s1.y; a1.z += v1 * s1.z; a1.w += v1 * s1.w;
  }
  if (j < j1) {
    int2 e0 = edges[j];
    int p0 = flag[e0.x] - 1;
    const float4 s0 = *(const float4*)(e2c + (size_t)p0 * DDIM + li * 4);
    float v0 = __int_as_float(e0.y);
    a0.x += v0 * s0.x; a0.y += v0 * s0.y; a0.z += v0 * s0.z; a0.w += v0 * s0.w;
  }
  const float4 e0v = *(const float4*)(emb + (size_t)s * DDIM + li * 4);
  const float4 e1r = *(const float4*)(e1 + (size_t)s * DDIM + li * 4);
  int ps = flag[s] - 1;
  const float4 e2v = *(const float4*)(e2c + (size_t)ps * DDIM + li * 4);
  float4 o;
  o.x = (e0v.x + e1r.x + e2v.x + a0.x + a1.x) * 0.25f;
  o.y = (e0v.y + e1r.y + e2v.y + a0.y + a1.y) * 0.25f;
  o.z = (e0v.z + e1r.z + e2v.z + a0.z + a1.z) * 0.25f;
  o.w = (e0v.w + e1r.w + e2v.w + a0.w + a1.w) * 0.25f;
  float* row = (qi < B_C) ? uf + (size_t)qi * CDIM : itf + (size_t)(qi - B_C) * CDIM;
  *(float4*)(row + li * 4) = o;
}

// ---------------------------------------------------------------- fused features
__device__ inline void xr4(float4& a) {
  a.x += __shfl_xor(a.x, 16, 64); a.y += __shfl_xor(a.y, 16, 64);
  a.z += __shfl_xor(a.z, 16, 64); a.w += __shfl_xor(a.w, 16, 64);
  a.x += __shfl_xor(a.x, 32, 64); a.y += __shfl_xor(a.y, 32, 64);
  a.z += __shfl_xor(a.z, 32, 64); a.w += __shfl_xor(a.w, 32, 64);
}

__global__ __launch_bounds__(256) void feat_kernel(
    const float* __restrict__ emb, const float* __restrict__ cate_table,
    const int* __restrict__ cates, const int* __restrict__ cate_lens,
    const int* __restrict__ items, const int* __restrict__ ihm,
    const int* __restrict__ ihl, const int* __restrict__ uhm,
    const int* __restrict__ uhl, float* __restrict__ uf,
    float* __restrict__ itf) {
  int tid = threadIdx.x;
  int wave = tid >> 6, w = tid & 63, g = w >> 4, li = w & 15;
  int q = blockIdx.x * 4 + wave;
  if (q < B_C) {
    // ---- user features
    int b = q;
    int len = ihl[b];
    float4 su = {0.f, 0.f, 0.f, 0.f}, sc = {0.f, 0.f, 0.f, 0.f};
    for (int h = g; h < len; h += 4) {
      int it = ihm[b * HIST_C + h];
      const float4 iv = *(const float4*)(emb + ((size_t)NU + it) * DDIM + li * 4);
      su.x += iv.x; su.y += iv.y; su.z += iv.z; su.w += iv.w;
      int cl = cate_lens[it];
      float4 cs = {0.f, 0.f, 0.f, 0.f};
      for (int c = 0; c < cl; ++c) {
        const float4 cv = *(const float4*)(cate_table + (size_t)cates[it * MC_C + c] * DDIM + li * 4);
        cs.x += cv.x; cs.y += cv.y; cs.z += cv.z; cs.w += cv.w;
      }
      float icl = 1.f / (float)cl;
      sc.x += cs.x * icl; sc.y += cs.y * icl; sc.z += cs.z * icl; sc.w += cs.w * icl;
    }
    xr4(su); xr4(sc);
    float inv = 1.f / (float)len;
    float* urow = uf + (size_t)b * CDIM;
    if (g == 0) {
      float4 o = {su.x * inv, su.y * inv, su.z * inv, su.w * inv};
      *(float4*)(urow + 64 + li * 4) = o;
    } else if (g == 1) {
      float4 o = {sc.x * inv, sc.y * inv, sc.z * inv, sc.w * inv};
      *(float4*)(urow + 128 + li * 4) = o;
    }
  } else {
    // ---- item features
    int b = q - B_C;
    int it = items[b];
    int cl = cate_lens[it];
    float4 cs = {0.f, 0.f, 0.f, 0.f};
    for (int c = g; c < cl; c += 4) {
      const float4 cv = *(const float4*)(cate_table + (size_t)cates[it * MC_C + c] * DDIM + li * 4);
      cs.x += cv.x; cs.y += cv.y; cs.z += cv.z; cs.w += cv.w;
    }
    int ul = uhl[b];
    float4 hs = {0.f, 0.f, 0.f, 0.f};
    for (int h = g; h < ul; h += 4) {
      const float4 hv = *(const float4*)(emb + (size_t)uhm[b * UHIST_C + h] * DDIM + li * 4);
      hs.x += hv.x; hs.y += hv.y; hs.z += hv.z; hs.w += hv.w;
    }
    xr4(cs); xr4(hs);
    float* irow = itf + (size_t)b * CDIM;
    if (g == 0) {
      float icl = 1.f / (float)cl;
      float4 o = {cs.x * icl, cs.y * icl, cs.z * icl, cs.w * icl};
      *(float4*)(irow + 64 + li * 4) = o;
    } else if (g == 1) {
      float iul = 1.f / (float)ul;
      float4 o = {hs.x * iul, hs.y * iul, hs.z * iul, hs.w * iul};
      *(float4*)(irow + 128 + li * 4) = o;
    }
  }
}

// ---------------------------------------------------------------- layernorm
__global__ __launch_bounds__(64) void ln_kernel(
    const float* __restrict__ uf, const float* __restrict__ itf,
    const float* __restrict__ lnw, const float* __restrict__ lnb,
    float* __restrict__ y) {
  int b = blockIdx.x, p = blockIdx.y, t = threadIdx.x;
  const float* x = ((p < 2) ? uf : itf) + (size_t)b * CDIM;
  float v0 = x[t], v1 = x[t + 64], v2 = x[t + 128];
  float s = v0 + v1 + v2;
#pragma unroll
  for (int off = 32; off; off >>= 1) s += __shfl_down(s, off, 64);
  float mu = __shfl(s, 0, 64) * (1.f / 192.f);
  float d0 = v0 - mu, d1 = v1 - mu, d2 = v2 - mu;
  float q = d0 * d0 + d1 * d1 + d2 * d2;
#pragma unroll
  for (int off = 32; off; off >>= 1) q += __shfl_down(q, off, 64);
  float var = __shfl(q, 0, 64) * (1.f / 192.f);
  float rs = 1.f / sqrtf(var + 1e-5f);
  float* yo = y + ((size_t)p * B_C + b) * CDIM;
  const float* w = lnw + p * CDIM;
  const float* bb = lnb + p * CDIM;
  yo[t]       = d0 * rs * w[t]       + bb[t];
  yo[t + 64]  = d1 * rs * w[t + 64]  + bb[t + 64];
  yo[t + 128] = d2 * rs * w[t + 128] + bb[t + 128];
}

// ---------------------------------------------------------------- GEMM1: h = relu(y@W1 + b1)
__global__ __launch_bounds__(256) void gemm1_kernel(
    const float* __restrict__ y, const float* __restrict__ w1,
    const float* __restrict__ b1, float* __restrict__ h) {
  int p = blockIdx.z;
  const float* A = y + (size_t)p * B_C * CDIM;
  const float* Bm = w1 + (size_t)p * CDIM * IDIM;
  const float* bias = b1 + p * IDIM;
  float* H = h + (size_t)p * B_C * IDIM;
  int r0 = blockIdx.x * 64, c0 = blockIdx.y * 64;
  __shared__ float As[64][68];
  __shared__ float Bs[64][64];
  int tid = threadIdx.x;
  int lr = tid >> 4, lc = (tid & 15) * 4;
  int tx = tid & 15, ty = tid >> 4;
  float acc[4][4] = {};
  for (int k0 = 0; k0 < CDIM; k0 += 64) {
    __syncthreads();
#pragma unroll
    for (int rr = 0; rr < 64; rr += 16) {
      float4 a = *(const float4*)&A[(size_t)(r0 + lr + rr) * CDIM + k0 + lc];
      *(float4*)&As[lr + rr][lc] = a;
      float4 bv = *(const float4*)&Bm[(size_t)(k0 + lr + rr) * IDIM + c0 + lc];
      *(float4*)&Bs[lr + rr][lc] = bv;
    }
    __syncthreads();
#pragma unroll
    for (int k = 0; k < 64; k += 4) {
      float4 a[4], bb[4];
#pragma unroll
      for (int i = 0; i < 4; ++i) a[i] = *(const float4*)&As[ty * 4 + i][k];
#pragma unroll
      for (int kk = 0; kk < 4; ++kk) bb[kk] = *(const float4*)&Bs[k + kk][tx * 4];
#pragma unroll
      for (int i = 0; i < 4; ++i) {
        const float av[4] = {a[i].x, a[i].y, a[i].z, a[i].w};
#pragma unroll
        for (int kk = 0; kk < 4; ++kk) {
          acc[i][0] += av[kk] * bb[kk].x;
          acc[i][1] += av[kk] * bb[kk].y;
          acc[i][2] += av[kk] * bb[kk].z;
          acc[i][3] += av[kk] * bb[kk].w;
        }
      }
    }
  }
  int c = c0 + tx * 4;
#pragma unroll
  for (int i = 0; i < 4; ++i) {
    int row = r0 + ty * 4 + i;
    float4 o;
    o.x = fmaxf(acc[i][0] + bias[c + 0], 0.f);
    o.y = fmaxf(acc[i][1] + bias[c + 1], 0.f);
    o.z = fmaxf(acc[i][2] + bias[c + 2], 0.f);
    o.w = fmaxf(acc[i][3] + bias[c + 3], 0.f);
    *(float4*)&H[(size_t)row * IDIM + c] = o;
  }
}

// ---------------------------------------------------------------- GEMM2: z = sum_i h_i@W2_i + b2s + 2x
__global__ __launch_bounds__(256) void gemm2_kernel(
    const float* __restrict__ h, const float* __restrict__ w2,
    const float* __restrict__ b2, const float* __restrict__ uf,
    const float* __restrict__ itf, float* __restrict__ zu, float* __restrict__ zi) {
  int s = blockIdx.z;
  const float* X = s ? itf : uf;
  float* Z = s ? zi : zu;
  int r0 = blockIdx.x * 64, c0 = blockIdx.y * 64;
  __shared__ float As[64][68];
  __shared__ float Bs[64][64];
  int tid = threadIdx.x;
  int lr = tid >> 4, lc = (tid & 15) * 4;
  int tx = tid & 15, ty = tid >> 4;
  float acc[4][4] = {};
  for (int pi = 0; pi < 2; ++pi) {
    int p = s * 2 + pi;
    const float* A = h + (size_t)p * B_C * IDIM;
    const float* Bm = w2 + (size_t)p * IDIM * CDIM;
    for (int k0 = 0; k0 < IDIM; k0 += 64) {
      __syncthreads();
#pragma unroll
      for (int rr = 0; rr < 64; rr += 16) {
        float4 a = *(const float4*)&A[(size_t)(r0 + lr + rr) * IDIM + k0 + lc];
        *(float4*)&As[lr + rr][lc] = a;
        float4 bv = *(const float4*)&Bm[(size_t)(k0 + lr + rr) * CDIM + c0 + lc];
        *(float4*)&Bs[lr + rr][lc] = bv;
      }
      __syncthreads();
#pragma unroll
      for (int k = 0; k < 64; k += 4) {
        float4 a[4], bb[4];
#pragma unroll
        for (int i = 0; i < 4; ++i) a[i] = *(const float4*)&As[ty * 4 + i][k];
#pragma unroll
        for (int kk = 0; kk < 4; ++kk) bb[kk] = *(const float4*)&Bs[k + kk][tx * 4];
#pragma unroll
        for (int i = 0; i < 4; ++i) {
          const float av[4] = {a[i].x, a[i].y, a[i].z, a[i].w};
#pragma unroll
          for (int kk = 0; kk < 4; ++kk) {
            acc[i][0] += av[kk] * bb[kk].x;
            acc[i][1] += av[kk] * bb[kk].y;
            acc[i][2] += av[kk] * bb[kk].z;
            acc[i][3] += av[kk] * bb[kk].w;
          }
        }
      }
    }
  }
  int c = c0 + tx * 4;
  float bs0 = b2[(s * 2) * CDIM + c + 0] + b2[(s * 2 + 1) * CDIM + c + 0];
  float bs1 = b2[(s * 2) * CDIM + c + 1] + b2[(s * 2 + 1) * CDIM + c + 1];
  float bs2 = b2[(s * 2) * CDIM + c + 2] + b2[(s * 2 + 1) * CDIM + c + 2];
  float bs3 = b2[(s * 2) * CDIM + c + 3] + b2[(s * 2 + 1) * CDIM + c + 3];
#pragma unroll
  for (int i = 0; i < 4; ++i) {
    int row = r0 + ty * 4 + i;
    float4 x4 = *(const float4*)&X[(size_t)row * CDIM + c];
    float4 o;
    o.x = acc[i][0] + bs0 + 2.f * x4.x;
    o.y = acc[i][1] + bs1 + 2.f * x4.y;
    o.z = acc[i][2] + bs2 + 2.f * x4.z;
    o.w = acc[i][3] + bs3 + 2.f * x4.w;
    *(float4*)&Z[(size_t)row * CDIM + c] = o;
  }
}

// ---------------------------------------------------------------- final L2 normalize
__global__ __launch_bounds__(64) void norm_kernel(
    const float* __restrict__ zu, const float* __restrict__ zi,
    float* __restrict__ out) {
  int b = blockIdx.x, s = blockIdx.y, t = threadIdx.x;
  const float* z = (s ? zi : zu) + (size_t)b * CDIM;
  float v0 = z[t], v1 = z[t + 64], v2 = z[t + 128];
  float q = v0 * v0 + v1 * v1 + v2 * v2;
#pragma unroll
  for (int off = 32; off; off >>= 1) q += __shfl_down(q, off, 64);
  float n = sqrtf(__shfl(q, 0, 64));
  float inv = 1.f / fmaxf(n, 1e-12f);
  float* o = out + (size_t)s * B_C * CDIM + (size_t)b * CDIM;
  o[t] = v0 * inv;
  o[t + 64] = v1 * inv;
  o[t + 128] = v2 * inv;
}

// ---------------------------------------------------------------- launch
extern "C" void kernel_launch(void* const* d_in, const int* in_sizes, int n_in,
                              void* d_out, int out_size, void* d_ws, size_t ws_size,
                              hipStream_t stream) {
  const float* emb   = (const float*)d_in[0];
  const float* cate  = (const float*)d_in[1];
  const float* avals = (const float*)d_in[2];
  const float* lnw   = (const float*)d_in[3];
  const float* lnb   = (const float*)d_in[4];
  const float* w1    = (const float*)d_in[5];
  const float* b1    = (const float*)d_in[6];
  const float* w2    = (const float*)d_in[7];
  const float* b2    = (const float*)d_in[8];
  const int* arows   = (const int*)d_in[9];
  const int* acols   = (const int*)d_in[10];
  const int* cates_  = (const int*)d_in[11];
  const int* clens   = (const int*)d_in[12];
  const int* users   = (const int*)d_in[13];
  const int* items   = (const int*)d_in[14];
  const int* ihm     = (const int*)d_in[15];
  const int* ihl     = (const int*)d_in[16];
  const int* uhm     = (const int*)d_in[17];
  const int* uhl     = (const int*)d_in[18];
  float* out = (float*)d_out;

  float* W = (float*)d_ws;
  float* e1      = W;                         //  9,600,000 f
  float* e2c     = W + 9600000;               //  6,029,312 f (MAXF*64)
  int2*  edges   = (int2*)(W + 15629312);     //  2,400,000 int2
  int*   row_ptr = (int*)(W + 20429312);      //  150,532 i
  int*   fillp   = (int*)(W + 20579844);      //  150,016 i
  int*   deg     = (int*)(W + 20729860);      //  150,528 i  (deg|flag|cnt: one memset)
  int*   flag    = (int*)(W + 20880388);      //  150,016 i
  int*   cnt     = (int*)(W + 21030404);      //  64 i
  int*   list    = (int*)(W + 21030468);      //  94,208 i
  int*   bsums   = (int*)(W + 21124676);      //  256 i
  float* uf      = W + 21124932;              //  786,432 f
  float* itf     = W + 21911364;              //  786,432 f (end 22,697,796 f = 90.8 MB)
  // post-GNN reuse:
  float* y  = e1;                             // [4][B][192] = 3,145,728 f
  float* h  = e1 + 3145728;                   // [4][B][384] = 6,291,456 f
  float* zu = e2c;                            // 786,432 f
  float* zi = e2c + 786432;                   // 786,432 f

  // ---- CSR build (int2-interleaved edges)
  (void)hipMemsetAsync(deg, 0, (150528 + 150016 + 64) * sizeof(int), stream);  // deg|flag|cnt
  deg_kernel<<<(NNZ_C + 255) / 256, 256, 0, stream>>>(arows, deg);
  scan_reduce<<<SCAN_B, 1024, 0, stream>>>(deg, bsums);
  scan_final<<<SCAN_B, 1024, 0, stream>>>(deg, bsums, row_ptr, fillp);
  csr_fill<<<(NNZ_C + 255) / 256, 256, 0, stream>>>(arows, acols, avals, fillp, edges);

  // ---- frontier = seeds ∪ N(seeds); compact to list/slots
  mark_kernel<<<(2 * B_C + 255) / 256, 256, 0, stream>>>(users, items, row_ptr, edges, flag);
  compact_kernel<<<(NN + 255) / 256, 256, 0, stream>>>(flag, list, cnt);

  // ---- GNN: e1 full gather; e2 masked+compacted; e3 fused into seed_finish
  spmm_gather4<<<NN / 16, 256, 0, stream>>>(emb, e1, row_ptr, edges);
  spmm_gather4_masked<<<MAXF / 16, 256, 0, stream>>>(e1, e2c, row_ptr, edges, list, cnt);
  seed_finish<<<(2 * B_C) / 16, 256, 0, stream>>>(emb, e1, e2c, flag, row_ptr,
                                                  edges, users, items, uf, itf);

  // ---- features (cols 64..192 of uf/itf)
  feat_kernel<<<(2 * B_C) / 4, 256, 0, stream>>>(emb, cate, cates_, clens, items,
                                                 ihm, ihl, uhm, uhl, uf, itf);

  // ---- MLP blocks
  ln_kernel<<<dim3(B_C, 4), 64, 0, stream>>>(uf, itf, lnw, lnb, y);
  gemm1_kernel<<<dim3(B_C / 64, IDIM / 64, 4), 256, 0, stream>>>(y, w1, b1, h);
  gemm2_kernel<<<dim3(B_C / 64, CDIM / 64, 2), 256, 0, stream>>>(h, w2, b2, uf, itf, zu, zi);
  norm_kernel<<<dim3(B_C, 2), 64, 0, stream>>>(zu, zi, out);
}

// Round 7
// 692.398 us; speedup vs baseline: 1.0550x; 1.0550x over previous
//
#include <hip/hip_runtime.h>
#include <hip/hip_bf16.h>
#include <cstdint>
#include <cstddef>

#define NU      100000
#define NN      150000
#define DDIM    64
#define NNZ_C   2400000
#define B_C     4096
#define HIST_C  50
#define UHIST_C 30
#define MC_C    5
#define CDIM    192
#define IDIM    384
#define SCAN_B  147
#define SCAN_N  (SCAN_B * 1024)   // 150528 >= NN, padded for scan
#define MAXF    96256             // frontier slots (expected ~89.1K); multiple of 16

// ---------------------------------------------------------------- CSR build
__global__ __launch_bounds__(256) void deg_kernel(
    const int* __restrict__ rows, int* __restrict__ deg) {
  int e = blockIdx.x * 256 + threadIdx.x;
  if (e < NNZ_C) atomicAdd(&deg[rows[e]], 1);
}

// generic block-sum over a 0/1-or-count array of SCAN_N ints
__global__ __launch_bounds__(1024) void scan_reduce(
    const int* __restrict__ arr, int* __restrict__ bsums) {
  __shared__ int s[1024];
  int t = threadIdx.x;
  s[t] = arr[blockIdx.x * 1024 + t];
  __syncthreads();
  for (int off = 512; off; off >>= 1) {
    if (t < off) s[t] += s[t + off];
    __syncthreads();
  }
  if (t == 0) bsums[blockIdx.x] = s[0];
}

// fused: in-block prefix over bsums + local scan; writes row_ptr AND fillp
__global__ __launch_bounds__(1024) void scan_final(
    const int* __restrict__ deg, const int* __restrict__ bsums,
    int* __restrict__ row_ptr, int* __restrict__ fillp) {
  __shared__ int pre[1024];
  __shared__ int s[1024];
  int t = threadIdx.x;
  pre[t] = (t < (int)blockIdx.x) ? bsums[t] : 0;
  __syncthreads();
  for (int off = 512; off; off >>= 1) {
    if (t < off) pre[t] += pre[t + off];
    __syncthreads();
  }
  int base = pre[0];
  __syncthreads();
  int i = blockIdx.x * 1024 + t;
  int v = deg[i];
  s[t] = v;
  __syncthreads();
  for (int off = 1; off < 1024; off <<= 1) {
    int u = (t >= off) ? s[t - off] : 0;
    __syncthreads();
    s[t] += u;
    __syncthreads();
  }
  int rp = base + s[t] - v;
  row_ptr[i] = rp;
  if (i < NN) fillp[i] = rp;
  if (i == SCAN_N - 1) row_ptr[SCAN_N] = base + s[t];
}

__global__ __launch_bounds__(256) void csr_fill(
    const int* __restrict__ rows, const int* __restrict__ cols,
    const float* __restrict__ vals, int* __restrict__ fillp,
    int2* __restrict__ edges) {
  int e = blockIdx.x * 256 + threadIdx.x;
  if (e >= NNZ_C) return;
  int r = rows[e];
  int pos = atomicAdd(&fillp[r], 1);
  edges[pos] = make_int2(cols[e], __float_as_int(vals[e]));
}

// ---------------------------------------------------------------- frontier mark + deterministic compact
__global__ __launch_bounds__(256) void mark_kernel(
    const int* __restrict__ users, const int* __restrict__ items,
    const int* __restrict__ row_ptr, const int2* __restrict__ edges,
    int* __restrict__ flag) {
  int t = blockIdx.x * 256 + threadIdx.x;
  if (t >= 2 * B_C) return;
  int s = (t < B_C) ? users[t] : items[t - B_C] + NU;
  flag[s] = 1;
  int j0 = row_ptr[s], j1 = row_ptr[s + 1];
  for (int j = j0; j < j1; ++j) flag[edges[j].x] = 1;
}

// deterministic compaction: slot = exclusive prefix sum of flag (0/1)
__global__ __launch_bounds__(1024) void compact_scan(
    int* __restrict__ flag, const int* __restrict__ bsums2,
    int* __restrict__ list, int* __restrict__ cnt) {
  __shared__ int pre[1024];
  __shared__ int s[1024];
  int t = threadIdx.x;
  pre[t] = (t < (int)blockIdx.x) ? bsums2[t] : 0;
  __syncthreads();
  for (int off = 512; off; off >>= 1) {
    if (t < off) pre[t] += pre[t + off];
    __syncthreads();
  }
  int base = pre[0];
  __syncthreads();
  int i = blockIdx.x * 1024 + t;
  int v = flag[i];
  s[t] = v;
  __syncthreads();
  for (int off = 1; off < 1024; off <<= 1) {
    int u = (t >= off) ? s[t - off] : 0;
    __syncthreads();
    s[t] += u;
    __syncthreads();
  }
  int slot = base + s[t] - v;  // exclusive
  if (v) {
    if (slot < MAXF) { list[slot] = i; flag[i] = slot + 1; }
    else flag[i] = 0;
  }
  if (i == SCAN_N - 1) {
    int tot = base + s[t];
    cnt[0] = (tot < MAXF) ? tot : MAXF;
  }
}

// ---------------------------------------------------------------- layer-1 gather SpMM
__global__ __launch_bounds__(256) void spmm_gather4(
    const float* __restrict__ src, float* __restrict__ dst,
    const int* __restrict__ row_ptr, const int2* __restrict__ edges) {
  int tid = threadIdx.x;
  int wave = tid >> 6, w = tid & 63, g = w >> 4, li = w & 15;
  int r = blockIdx.x * 16 + wave * 4 + g;
  int j0 = row_ptr[r], j1 = row_ptr[r + 1];
  float4 a0 = {0.f, 0.f, 0.f, 0.f}, a1 = {0.f, 0.f, 0.f, 0.f};
  int j = j0;
  for (; j + 2 <= j1; j += 2) {
    int2 e0 = edges[j], e1 = edges[j + 1];
    const float4 s0 = *(const float4*)(src + (size_t)e0.x * DDIM + li * 4);
    const float4 s1 = *(const float4*)(src + (size_t)e1.x * DDIM + li * 4);
    float v0 = __int_as_float(e0.y), v1 = __int_as_float(e1.y);
    a0.x += v0 * s0.x; a0.y += v0 * s0.y; a0.z += v0 * s0.z; a0.w += v0 * s0.w;
    a1.x += v1 * s1.x; a1.y += v1 * s1.y; a1.z += v1 * s1.z; a1.w += v1 * s1.w;
  }
  if (j < j1) {
    int2 e0 = edges[j];
    const float4 s0 = *(const float4*)(src + (size_t)e0.x * DDIM + li * 4);
    float v0 = __int_as_float(e0.y);
    a0.x += v0 * s0.x; a0.y += v0 * s0.y; a0.z += v0 * s0.z; a0.w += v0 * s0.w;
  }
  float4 o = {a0.x + a1.x, a0.y + a1.y, a0.z + a1.z, a0.w + a1.w};
  *(float4*)(dst + (size_t)r * DDIM + li * 4) = o;
}

// ---------------------------------------------------------------- masked layer-2 (compacted output)
__global__ __launch_bounds__(256) void spmm_gather4_masked(
    const float* __restrict__ src, float* __restrict__ dstc,
    const int* __restrict__ row_ptr, const int2* __restrict__ edges,
    const int* __restrict__ list, const int* __restrict__ cnt) {
  int tid = threadIdx.x;
  int wave = tid >> 6, w = tid & 63, g = w >> 4, li = w & 15;
  int p = blockIdx.x * 16 + wave * 4 + g;
  if (p >= cnt[0]) return;
  int r = list[p];
  int j0 = row_ptr[r], j1 = row_ptr[r + 1];
  float4 a0 = {0.f, 0.f, 0.f, 0.f}, a1 = {0.f, 0.f, 0.f, 0.f};
  int j = j0;
  for (; j + 2 <= j1; j += 2) {
    int2 e0 = edges[j], e1 = edges[j + 1];
    const float4 s0 = *(const float4*)(src + (size_t)e0.x * DDIM + li * 4);
    const float4 s1 = *(const float4*)(src + (size_t)e1.x * DDIM + li * 4);
    float v0 = __int_as_float(e0.y), v1 = __int_as_float(e1.y);
    a0.x += v0 * s0.x; a0.y += v0 * s0.y; a0.z += v0 * s0.z; a0.w += v0 * s0.w;
    a1.x += v1 * s1.x; a1.y += v1 * s1.y; a1.z += v1 * s1.z; a1.w += v1 * s1.w;
  }
  if (j < j1) {
    int2 e0 = edges[j];
    const float4 s0 = *(const float4*)(src + (size_t)e0.x * DDIM + li * 4);
    float v0 = __int_as_float(e0.y);
    a0.x += v0 * s0.x; a0.y += v0 * s0.y; a0.z += v0 * s0.z; a0.w += v0 * s0.w;
  }
  float4 o = {a0.x + a1.x, a0.y + a1.y, a0.z + a1.z, a0.w + a1.w};
  *(float4*)(dstc + (size_t)p * DDIM + li * 4) = o;
}

// ---------------------------------------------------------------- seed finish: g=(e0+e1+e2+e3)/4 -> uf/itf col 0
__global__ __launch_bounds__(256) void seed_finish(
    const float* __restrict__ emb, const float* __restrict__ e1,
    const float* __restrict__ e2c, const int* __restrict__ flag,
    const int* __restrict__ row_ptr, const int2* __restrict__ edges,
    const int* __restrict__ users, const int* __restrict__ items,
    float* __restrict__ uf, float* __restrict__ itf) {
  int tid = threadIdx.x;
  int wave = tid >> 6, w = tid & 63, g = w >> 4, li = w & 15;
  int qi = blockIdx.x * 16 + wave * 4 + g;
  int s = (qi < B_C) ? users[qi] : items[qi - B_C] + NU;
  int j0 = row_ptr[s], j1 = row_ptr[s + 1];
  float4 a0 = {0.f, 0.f, 0.f, 0.f}, a1 = {0.f, 0.f, 0.f, 0.f};
  int j = j0;
  for (; j + 2 <= j1; j += 2) {
    int2 e0 = edges[j], e1v = edges[j + 1];
    int p0 = flag[e0.x] - 1; p0 = p0 > 0 ? p0 : 0;
    int p1 = flag[e1v.x] - 1; p1 = p1 > 0 ? p1 : 0;
    const float4 s0 = *(const float4*)(e2c + (size_t)p0 * DDIM + li * 4);
    const float4 s1 = *(const float4*)(e2c + (size_t)p1 * DDIM + li * 4);
    float v0 = __int_as_float(e0.y), v1 = __int_as_float(e1v.y);
    a0.x += v0 * s0.x; a0.y += v0 * s0.y; a0.z += v0 * s0.z; a0.w += v0 * s0.w;
    a1.x += v1 * s1.x; a1.y += v1 * s1.y; a1.z += v1 * s1.z; a1.w += v1 * s1.w;
  }
  if (j < j1) {
    int2 e0 = edges[j];
    int p0 = flag[e0.x] - 1; p0 = p0 > 0 ? p0 : 0;
    const float4 s0 = *(const float4*)(e2c + (size_t)p0 * DDIM + li * 4);
    float v0 = __int_as_float(e0.y);
    a0.x += v0 * s0.x; a0.y += v0 * s0.y; a0.z += v0 * s0.z; a0.w += v0 * s0.w;
  }
  const float4 e0v = *(const float4*)(emb + (size_t)s * DDIM + li * 4);
  const float4 e1r = *(const float4*)(e1 + (size_t)s * DDIM + li * 4);
  int ps = flag[s] - 1; ps = ps > 0 ? ps : 0;
  const float4 e2v = *(const float4*)(e2c + (size_t)ps * DDIM + li * 4);
  float4 o;
  o.x = (e0v.x + e1r.x + e2v.x + a0.x + a1.x) * 0.25f;
  o.y = (e0v.y + e1r.y + e2v.y + a0.y + a1.y) * 0.25f;
  o.z = (e0v.z + e1r.z + e2v.z + a0.z + a1.z) * 0.25f;
  o.w = (e0v.w + e1r.w + e2v.w + a0.w + a1.w) * 0.25f;
  float* row = (qi < B_C) ? uf + (size_t)qi * CDIM : itf + (size_t)(qi - B_C) * CDIM;
  *(float4*)(row + li * 4) = o;
}

// ---------------------------------------------------------------- fused features
__device__ inline void xr4(float4& a) {
  a.x += __shfl_xor(a.x, 16, 64); a.y += __shfl_xor(a.y, 16, 64);
  a.z += __shfl_xor(a.z, 16, 64); a.w += __shfl_xor(a.w, 16, 64);
  a.x += __shfl_xor(a.x, 32, 64); a.y += __shfl_xor(a.y, 32, 64);
  a.z += __shfl_xor(a.z, 32, 64); a.w += __shfl_xor(a.w, 32, 64);
}

__global__ __launch_bounds__(256) void feat_kernel(
    const float* __restrict__ emb, const float* __restrict__ cate_table,
    const int* __restrict__ cates, const int* __restrict__ cate_lens,
    const int* __restrict__ items, const int* __restrict__ ihm,
    const int* __restrict__ ihl, const int* __restrict__ uhm,
    const int* __restrict__ uhl, float* __restrict__ uf,
    float* __restrict__ itf) {
  int tid = threadIdx.x;
  int wave = tid >> 6, w = tid & 63, g = w >> 4, li = w & 15;
  int q = blockIdx.x * 4 + wave;
  if (q < B_C) {
    int b = q;
    int len = ihl[b];
    float4 su = {0.f, 0.f, 0.f, 0.f}, sc = {0.f, 0.f, 0.f, 0.f};
    for (int h = g; h < len; h += 4) {
      int it = ihm[b * HIST_C + h];
      const float4 iv = *(const float4*)(emb + ((size_t)NU + it) * DDIM + li * 4);
      su.x += iv.x; su.y += iv.y; su.z += iv.z; su.w += iv.w;
      int cl = cate_lens[it];
      float4 cs = {0.f, 0.f, 0.f, 0.f};
      for (int c = 0; c < cl; ++c) {
        const float4 cv = *(const float4*)(cate_table + (size_t)cates[it * MC_C + c] * DDIM + li * 4);
        cs.x += cv.x; cs.y += cv.y; cs.z += cv.z; cs.w += cv.w;
      }
      float icl = 1.f / (float)cl;
      sc.x += cs.x * icl; sc.y += cs.y * icl; sc.z += cs.z * icl; sc.w += cs.w * icl;
    }
    xr4(su); xr4(sc);
    float inv = 1.f / (float)len;
    float* urow = uf + (size_t)b * CDIM;
    if (g == 0) {
      float4 o = {su.x * inv, su.y * inv, su.z * inv, su.w * inv};
      *(float4*)(urow + 64 + li * 4) = o;
    } else if (g == 1) {
      float4 o = {sc.x * inv, sc.y * inv, sc.z * inv, sc.w * inv};
      *(float4*)(urow + 128 + li * 4) = o;
    }
  } else {
    int b = q - B_C;
    int it = items[b];
    int cl = cate_lens[it];
    float4 cs = {0.f, 0.f, 0.f, 0.f};
    for (int c = g; c < cl; c += 4) {
      const float4 cv = *(const float4*)(cate_table + (size_t)cates[it * MC_C + c] * DDIM + li * 4);
      cs.x += cv.x; cs.y += cv.y; cs.z += cv.z; cs.w += cv.w;
    }
    int ul = uhl[b];
    float4 hs = {0.f, 0.f, 0.f, 0.f};
    for (int h = g; h < ul; h += 4) {
      const float4 hv = *(const float4*)(emb + (size_t)uhm[b * UHIST_C + h] * DDIM + li * 4);
      hs.x += hv.x; hs.y += hv.y; hs.z += hv.z; hs.w += hv.w;
    }
    xr4(cs); xr4(hs);
    float* irow = itf + (size_t)b * CDIM;
    if (g == 0) {
      float icl = 1.f / (float)cl;
      float4 o = {cs.x * icl, cs.y * icl, cs.z * icl, cs.w * icl};
      *(float4*)(irow + 64 + li * 4) = o;
    } else if (g == 1) {
      float iul = 1.f / (float)ul;
      float4 o = {hs.x * iul, hs.y * iul, hs.z * iul, hs.w * iul};
      *(float4*)(irow + 128 + li * 4) = o;
    }
  }
}

// ---------------------------------------------------------------- layernorm
__global__ __launch_bounds__(64) void ln_kernel(
    const float* __restrict__ uf, const float* __restrict__ itf,
    const float* __restrict__ lnw, const float* __restrict__ lnb,
    float* __restrict__ y) {
  int b = blockIdx.x, p = blockIdx.y, t = threadIdx.x;
  const float* x = ((p < 2) ? uf : itf) + (size_t)b * CDIM;
  float v0 = x[t], v1 = x[t + 64], v2 = x[t + 128];
  float s = v0 + v1 + v2;
#pragma unroll
  for (int off = 32; off; off >>= 1) s += __shfl_down(s, off, 64);
  float mu = __shfl(s, 0, 64) * (1.f / 192.f);
  float d0 = v0 - mu, d1 = v1 - mu, d2 = v2 - mu;
  float q = d0 * d0 + d1 * d1 + d2 * d2;
#pragma unroll
  for (int off = 32; off; off >>= 1) q += __shfl_down(q, off, 64);
  float var = __shfl(q, 0, 64) * (1.f / 192.f);
  float rs = 1.f / sqrtf(var + 1e-5f);
  float* yo = y + ((size_t)p * B_C + b) * CDIM;
  const float* w = lnw + p * CDIM;
  const float* bb = lnb + p * CDIM;
  yo[t]       = d0 * rs * w[t]       + bb[t];
  yo[t + 64]  = d1 * rs * w[t + 64]  + bb[t + 64];
  yo[t + 128] = d2 * rs * w[t + 128] + bb[t + 128];
}

// ---------------------------------------------------------------- GEMM1: h = relu(y@W1 + b1)
__global__ __launch_bounds__(256) void gemm1_kernel(
    const float* __restrict__ y, const float* __restrict__ w1,
    const float* __restrict__ b1, float* __restrict__ h) {
  int p = blockIdx.z;
  const float* A = y + (size_t)p * B_C * CDIM;
  const float* Bm = w1 + (size_t)p * CDIM * IDIM;
  const float* bias = b1 + p * IDIM;
  float* H = h + (size_t)p * B_C * IDIM;
  int r0 = blockIdx.x * 64, c0 = blockIdx.y * 64;
  __shared__ float As[64][68];
  __shared__ float Bs[64][64];
  int tid = threadIdx.x;
  int lr = tid >> 4, lc = (tid & 15) * 4;
  int tx = tid & 15, ty = tid >> 4;
  float acc[4][4] = {};
  for (int k0 = 0; k0 < CDIM; k0 += 64) {
    __syncthreads();
#pragma unroll
    for (int rr = 0; rr < 64; rr += 16) {
      float4 a = *(const float4*)&A[(size_t)(r0 + lr + rr) * CDIM + k0 + lc];
      *(float4*)&As[lr + rr][lc] = a;
      float4 bv = *(const float4*)&Bm[(size_t)(k0 + lr + rr) * IDIM + c0 + lc];
      *(float4*)&Bs[lr + rr][lc] = bv;
    }
    __syncthreads();
#pragma unroll
    for (int k = 0; k < 64; k += 4) {
      float4 a[4], bb[4];
#pragma unroll
      for (int i = 0; i < 4; ++i) a[i] = *(const float4*)&As[ty * 4 + i][k];
#pragma unroll
      for (int kk = 0; kk < 4; ++kk) bb[kk] = *(const float4*)&Bs[k + kk][tx * 4];
#pragma unroll
      for (int i = 0; i < 4; ++i) {
        const float av[4] = {a[i].x, a[i].y, a[i].z, a[i].w};
#pragma unroll
        for (int kk = 0; kk < 4; ++kk) {
          acc[i][0] += av[kk] * bb[kk].x;
          acc[i][1] += av[kk] * bb[kk].y;
          acc[i][2] += av[kk] * bb[kk].z;
          acc[i][3] += av[kk] * bb[kk].w;
        }
      }
    }
  }
  int c = c0 + tx * 4;
#pragma unroll
  for (int i = 0; i < 4; ++i) {
    int row = r0 + ty * 4 + i;
    float4 o;
    o.x = fmaxf(acc[i][0] + bias[c + 0], 0.f);
    o.y = fmaxf(acc[i][1] + bias[c + 1], 0.f);
    o.z = fmaxf(acc[i][2] + bias[c + 2], 0.f);
    o.w = fmaxf(acc[i][3] + bias[c + 3], 0.f);
    *(float4*)&H[(size_t)row * IDIM + c] = o;
  }
}

// ---------------------------------------------------------------- GEMM2: z = sum_i h_i@W2_i + b2s + 2x
__global__ __launch_bounds__(256) void gemm2_kernel(
    const float* __restrict__ h, const float* __restrict__ w2,
    const float* __restrict__ b2, const float* __restrict__ uf,
    const float* __restrict__ itf, float* __restrict__ zu, float* __restrict__ zi) {
  int s = blockIdx.z;
  const float* X = s ? itf : uf;
  float* Z = s ? zi : zu;
  int r0 = blockIdx.x * 64, c0 = blockIdx.y * 64;
  __shared__ float As[64][68];
  __shared__ float Bs[64][64];
  int tid = threadIdx.x;
  int lr = tid >> 4, lc = (tid & 15) * 4;
  int tx = tid & 15, ty = tid >> 4;
  float acc[4][4] = {};
  for (int pi = 0; pi < 2; ++pi) {
    int p = s * 2 + pi;
    const float* A = h + (size_t)p * B_C * IDIM;
    const float* Bm = w2 + (size_t)p * IDIM * CDIM;
    for (int k0 = 0; k0 < IDIM; k0 += 64) {
      __syncthreads();
#pragma unroll
      for (int rr = 0; rr < 64; rr += 16) {
        float4 a = *(const float4*)&A[(size_t)(r0 + lr + rr) * IDIM + k0 + lc];
        *(float4*)&As[lr + rr][lc] = a;
        float4 bv = *(const float4*)&Bm[(size_t)(k0 + lr + rr) * CDIM + c0 + lc];
        *(float4*)&Bs[lr + rr][lc] = bv;
      }
      __syncthreads();
#pragma unroll
      for (int k = 0; k < 64; k += 4) {
        float4 a[4], bb[4];
#pragma unroll
        for (int i = 0; i < 4; ++i) a[i] = *(const float4*)&As[ty * 4 + i][k];
#pragma unroll
        for (int kk = 0; kk < 4; ++kk) bb[kk] = *(const float4*)&Bs[k + kk][tx * 4];
#pragma unroll
        for (int i = 0; i < 4; ++i) {
          const float av[4] = {a[i].x, a[i].y, a[i].z, a[i].w};
#pragma unroll
          for (int kk = 0; kk < 4; ++kk) {
            acc[i][0] += av[kk] * bb[kk].x;
            acc[i][1] += av[kk] * bb[kk].y;
            acc[i][2] += av[kk] * bb[kk].z;
            acc[i][3] += av[kk] * bb[kk].w;
          }
        }
      }
    }
  }
  int c = c0 + tx * 4;
  float bs0 = b2[(s * 2) * CDIM + c + 0] + b2[(s * 2 + 1) * CDIM + c + 0];
  float bs1 = b2[(s * 2) * CDIM + c + 1] + b2[(s * 2 + 1) * CDIM + c + 1];
  float bs2 = b2[(s * 2) * CDIM + c + 2] + b2[(s * 2 + 1) * CDIM + c + 2];
  float bs3 = b2[(s * 2) * CDIM + c + 3] + b2[(s * 2 + 1) * CDIM + c + 3];
#pragma unroll
  for (int i = 0; i < 4; ++i) {
    int row = r0 + ty * 4 + i;
    float4 x4 = *(const float4*)&X[(size_t)row * CDIM + c];
    float4 o;
    o.x = acc[i][0] + bs0 + 2.f * x4.x;
    o.y = acc[i][1] + bs1 + 2.f * x4.y;
    o.z = acc[i][2] + bs2 + 2.f * x4.z;
    o.w = acc[i][3] + bs3 + 2.f * x4.w;
    *(float4*)&Z[(size_t)row * CDIM + c] = o;
  }
}

// ---------------------------------------------------------------- final L2 normalize
__global__ __launch_bounds__(64) void norm_kernel(
    const float* __restrict__ zu, const float* __restrict__ zi,
    float* __restrict__ out) {
  int b = blockIdx.x, s = blockIdx.y, t = threadIdx.x;
  const float* z = (s ? zi : zu) + (size_t)b * CDIM;
  float v0 = z[t], v1 = z[t + 64], v2 = z[t + 128];
  float q = v0 * v0 + v1 * v1 + v2 * v2;
#pragma unroll
  for (int off = 32; off; off >>= 1) q += __shfl_down(q, off, 64);
  float n = sqrtf(__shfl(q, 0, 64));
  float inv = 1.f / fmaxf(n, 1e-12f);
  float* o = out + (size_t)s * B_C * CDIM + (size_t)b * CDIM;
  o[t] = v0 * inv;
  o[t + 64] = v1 * inv;
  o[t + 128] = v2 * inv;
}

// ---------------------------------------------------------------- launch
extern "C" void kernel_launch(void* const* d_in, const int* in_sizes, int n_in,
                              void* d_out, int out_size, void* d_ws, size_t ws_size,
                              hipStream_t stream) {
  const float* emb   = (const float*)d_in[0];
  const float* cate  = (const float*)d_in[1];
  const float* avals = (const float*)d_in[2];
  const float* lnw   = (const float*)d_in[3];
  const float* lnb   = (const float*)d_in[4];
  const float* w1    = (const float*)d_in[5];
  const float* b1    = (const float*)d_in[6];
  const float* w2    = (const float*)d_in[7];
  const float* b2    = (const float*)d_in[8];
  const int* arows   = (const int*)d_in[9];
  const int* acols   = (const int*)d_in[10];
  const int* cates_  = (const int*)d_in[11];
  const int* clens   = (const int*)d_in[12];
  const int* users   = (const int*)d_in[13];
  const int* items   = (const int*)d_in[14];
  const int* ihm     = (const int*)d_in[15];
  const int* ihl     = (const int*)d_in[16];
  const int* uhm     = (const int*)d_in[17];
  const int* uhl     = (const int*)d_in[18];
  float* out = (float*)d_out;

  float* W = (float*)d_ws;
  float* e1      = W;                         // 9,600,000 f
  float* e2c     = W + 9600000;               // 6,160,384 f (MAXF*64) -> 15,760,384
  int2*  edges   = (int2*)(W + 15760384);     // 2,400,000 int2 -> 20,560,384
  int*   row_ptr = (int*)(W + 20560384);      // 150,532 i -> 20,710,916
  int*   fillp   = (int*)(W + 20710916);      // 150,528 i -> 20,861,444
  int*   deg     = (int*)(W + 20861444);      // 150,528 i -> 21,011,972 (deg..cnt one memset)
  int*   flag    = (int*)(W + 21011972);      // 150,528 i -> 21,162,500 (padded for scan)
  int*   cnt     = (int*)(W + 21162500);      // 64 i -> 21,162,564
  int*   list    = (int*)(W + 21162564);      // 96,256 i -> 21,258,820
  int*   bsums   = (int*)(W + 21258820);      // 256 i -> 21,259,076
  int*   bsums2  = (int*)(W + 21259076);      // 256 i -> 21,259,332
  float* uf      = W + 21259332;              // 786,432 f -> 22,045,764
  float* itf     = W + 22045764;              // 786,432 f -> 22,832,196 (91.3 MB)
  // post-GNN reuse:
  float* y  = e1;                             // [4][B][192] = 3,145,728 f
  float* h  = e1 + 3145728;                   // [4][B][384] = 6,291,456 f
  float* zu = e2c;                            // 786,432 f
  float* zi = e2c + 786432;                   // 786,432 f

  // ---- CSR build (int2-interleaved edges)
  (void)hipMemsetAsync(deg, 0, (150528 + 150528 + 64) * sizeof(int), stream);
  deg_kernel<<<(NNZ_C + 255) / 256, 256, 0, stream>>>(arows, deg);
  scan_reduce<<<SCAN_B, 1024, 0, stream>>>(deg, bsums);
  scan_final<<<SCAN_B, 1024, 0, stream>>>(deg, bsums, row_ptr, fillp);
  csr_fill<<<(NNZ_C + 255) / 256, 256, 0, stream>>>(arows, acols, avals, fillp, edges);

  // ---- frontier = seeds + N(seeds); deterministic scan compaction
  mark_kernel<<<(2 * B_C + 255) / 256, 256, 0, stream>>>(users, items, row_ptr, edges, flag);
  scan_reduce<<<SCAN_B, 1024, 0, stream>>>(flag, bsums2);
  compact_scan<<<SCAN_B, 1024, 0, stream>>>(flag, bsums2, list, cnt);

  // ---- GNN: e1 full gather; e2 masked+compacted; e3 fused into seed_finish
  spmm_gather4<<<NN / 16, 256, 0, stream>>>(emb, e1, row_ptr, edges);
  spmm_gather4_masked<<<MAXF / 16, 256, 0, stream>>>(e1, e2c, row_ptr, edges, list, cnt);
  seed_finish<<<(2 * B_C) / 16, 256, 0, stream>>>(emb, e1, e2c, flag, row_ptr,
                                                  edges, users, items, uf, itf);

  // ---- features (cols 64..192 of uf/itf)
  feat_kernel<<<(2 * B_C) / 4, 256, 0, stream>>>(emb, cate, cates_, clens, items,
                                                 ihm, ihl, uhm, uhl, uf, itf);

  // ---- MLP blocks
  ln_kernel<<<dim3(B_C, 4), 64, 0, stream>>>(uf, itf, lnw, lnb, y);
  gemm1_kernel<<<dim3(B_C / 64, IDIM / 64, 4), 256, 0, stream>>>(y, w1, b1, h);
  gemm2_kernel<<<dim3(B_C / 64, CDIM / 64, 2), 256, 0, stream>>>(h, w2, b2, uf, itf, zu, zi);
  norm_kernel<<<dim3(B_C, 2), 64, 0, stream>>>(zu, zi, out);
}

// Round 8
// 586.406 us; speedup vs baseline: 1.2456x; 1.1807x over previous
//
#include <hip/hip_runtime.h>
#include <hip/hip_bf16.h>
#include <cstdint>
#include <cstddef>

#define NU      100000
#define NN      150000
#define DDIM    64
#define NNZ_C   2400000
#define B_C     4096
#define HIST_C  50
#define UHIST_C 30
#define MC_C    5
#define CDIM    192
#define IDIM    384
#define SCAN_B  147
#define SCAN_N  (SCAN_B * 1024)   // 150528 >= NN, padded for scan
#define MAXF    96256             // frontier slots (expected ~89.1K); multiple of 16

// ---------------------------------------------------------------- CSR build
// rank_kernel: deg histogram AND intra-row rank in one pass.
// 4 independent atomics per thread (strided for coalesced rows[] reads).
__global__ __launch_bounds__(256) void rank_kernel(
    const int* __restrict__ rows, int* __restrict__ deg, int* __restrict__ pos) {
  int base = blockIdx.x * 1024 + threadIdx.x;
#pragma unroll
  for (int k = 0; k < 4; ++k) {
    int e = base + k * 256;
    if (e < NNZ_C) pos[e] = atomicAdd(&deg[rows[e]], 1);
  }
}

// generic block-sum over an array of SCAN_N ints
__global__ __launch_bounds__(1024) void scan_reduce(
    const int* __restrict__ arr, int* __restrict__ bsums) {
  __shared__ int s[1024];
  int t = threadIdx.x;
  s[t] = arr[blockIdx.x * 1024 + t];
  __syncthreads();
  for (int off = 512; off; off >>= 1) {
    if (t < off) s[t] += s[t + off];
    __syncthreads();
  }
  if (t == 0) bsums[blockIdx.x] = s[0];
}

// fused: in-block prefix over bsums + local scan; writes row_ptr
__global__ __launch_bounds__(1024) void scan_final(
    const int* __restrict__ deg, const int* __restrict__ bsums,
    int* __restrict__ row_ptr) {
  __shared__ int pre[1024];
  __shared__ int s[1024];
  int t = threadIdx.x;
  pre[t] = (t < (int)blockIdx.x) ? bsums[t] : 0;
  __syncthreads();
  for (int off = 512; off; off >>= 1) {
    if (t < off) pre[t] += pre[t + off];
    __syncthreads();
  }
  int base = pre[0];
  __syncthreads();
  int i = blockIdx.x * 1024 + t;
  int v = deg[i];
  s[t] = v;
  __syncthreads();
  for (int off = 1; off < 1024; off <<= 1) {
    int u = (t >= off) ? s[t - off] : 0;
    __syncthreads();
    s[t] += u;
    __syncthreads();
  }
  row_ptr[i] = base + s[t] - v;
  if (i == SCAN_N - 1) row_ptr[SCAN_N] = base + s[t];
}

// atomic-free fill: position = row_ptr[r] + precomputed rank. Pure scatter.
__global__ __launch_bounds__(256) void csr_fill(
    const int* __restrict__ rows, const int* __restrict__ cols,
    const float* __restrict__ vals, const int* __restrict__ row_ptr,
    const int* __restrict__ pos, int2* __restrict__ edges) {
  int base = blockIdx.x * 1024 + threadIdx.x;
#pragma unroll
  for (int k = 0; k < 4; ++k) {
    int e = base + k * 256;
    if (e < NNZ_C) {
      int r = rows[e];
      edges[row_ptr[r] + pos[e]] = make_int2(cols[e], __float_as_int(vals[e]));
    }
  }
}

// ---------------------------------------------------------------- frontier mark + deterministic compact
__global__ __launch_bounds__(256) void mark_kernel(
    const int* __restrict__ users, const int* __restrict__ items,
    const int* __restrict__ row_ptr, const int2* __restrict__ edges,
    int* __restrict__ flag) {
  int t = blockIdx.x * 256 + threadIdx.x;
  if (t >= 2 * B_C) return;
  int s = (t < B_C) ? users[t] : items[t - B_C] + NU;
  flag[s] = 1;
  int j0 = row_ptr[s], j1 = row_ptr[s + 1];
  for (int j = j0; j < j1; ++j) flag[edges[j].x] = 1;
}

// deterministic compaction: slot = exclusive prefix sum of flag (0/1)
__global__ __launch_bounds__(1024) void compact_scan(
    int* __restrict__ flag, const int* __restrict__ bsums2,
    int* __restrict__ list, int* __restrict__ cnt) {
  __shared__ int pre[1024];
  __shared__ int s[1024];
  int t = threadIdx.x;
  pre[t] = (t < (int)blockIdx.x) ? bsums2[t] : 0;
  __syncthreads();
  for (int off = 512; off; off >>= 1) {
    if (t < off) pre[t] += pre[t + off];
    __syncthreads();
  }
  int base = pre[0];
  __syncthreads();
  int i = blockIdx.x * 1024 + t;
  int v = flag[i];
  s[t] = v;
  __syncthreads();
  for (int off = 1; off < 1024; off <<= 1) {
    int u = (t >= off) ? s[t - off] : 0;
    __syncthreads();
    s[t] += u;
    __syncthreads();
  }
  int slot = base + s[t] - v;  // exclusive
  if (v) {
    if (slot < MAXF) { list[slot] = i; flag[i] = slot + 1; }
    else flag[i] = 0;
  }
  if (i == SCAN_N - 1) {
    int tot = base + s[t];
    cnt[0] = (tot < MAXF) ? tot : MAXF;
  }
}

// ---------------------------------------------------------------- layer-1 gather SpMM
// 4 rows/wave, 16 lanes x float4 per row, unroll x4 -> 16 gather chains/wave
__global__ __launch_bounds__(256) void spmm_gather4(
    const float* __restrict__ src, float* __restrict__ dst,
    const int* __restrict__ row_ptr, const int2* __restrict__ edges) {
  int tid = threadIdx.x;
  int wave = tid >> 6, w = tid & 63, g = w >> 4, li = w & 15;
  int r = blockIdx.x * 16 + wave * 4 + g;
  int j0 = row_ptr[r], j1 = row_ptr[r + 1];
  float4 a0 = {0.f, 0.f, 0.f, 0.f}, a1 = {0.f, 0.f, 0.f, 0.f};
  float4 a2 = {0.f, 0.f, 0.f, 0.f}, a3 = {0.f, 0.f, 0.f, 0.f};
  int j = j0;
  for (; j + 4 <= j1; j += 4) {
    int2 e0 = edges[j], e1 = edges[j + 1], e2 = edges[j + 2], e3 = edges[j + 3];
    const float4 s0 = *(const float4*)(src + (size_t)e0.x * DDIM + li * 4);
    const float4 s1 = *(const float4*)(src + (size_t)e1.x * DDIM + li * 4);
    const float4 s2 = *(const float4*)(src + (size_t)e2.x * DDIM + li * 4);
    const float4 s3 = *(const float4*)(src + (size_t)e3.x * DDIM + li * 4);
    float v0 = __int_as_float(e0.y), v1 = __int_as_float(e1.y);
    float v2 = __int_as_float(e2.y), v3 = __int_as_float(e3.y);
    a0.x += v0 * s0.x; a0.y += v0 * s0.y; a0.z += v0 * s0.z; a0.w += v0 * s0.w;
    a1.x += v1 * s1.x; a1.y += v1 * s1.y; a1.z += v1 * s1.z; a1.w += v1 * s1.w;
    a2.x += v2 * s2.x; a2.y += v2 * s2.y; a2.z += v2 * s2.z; a2.w += v2 * s2.w;
    a3.x += v3 * s3.x; a3.y += v3 * s3.y; a3.z += v3 * s3.z; a3.w += v3 * s3.w;
  }
  for (; j < j1; ++j) {
    int2 e0 = edges[j];
    const float4 s0 = *(const float4*)(src + (size_t)e0.x * DDIM + li * 4);
    float v0 = __int_as_float(e0.y);
    a0.x += v0 * s0.x; a0.y += v0 * s0.y; a0.z += v0 * s0.z; a0.w += v0 * s0.w;
  }
  float4 o = {a0.x + a1.x + a2.x + a3.x, a0.y + a1.y + a2.y + a3.y,
              a0.z + a1.z + a2.z + a3.z, a0.w + a1.w + a2.w + a3.w};
  *(float4*)(dst + (size_t)r * DDIM + li * 4) = o;
}

// ---------------------------------------------------------------- masked layer-2 (compacted output)
__global__ __launch_bounds__(256) void spmm_gather4_masked(
    const float* __restrict__ src, float* __restrict__ dstc,
    const int* __restrict__ row_ptr, const int2* __restrict__ edges,
    const int* __restrict__ list, const int* __restrict__ cnt) {
  int tid = threadIdx.x;
  int wave = tid >> 6, w = tid & 63, g = w >> 4, li = w & 15;
  int p = blockIdx.x * 16 + wave * 4 + g;
  if (p >= cnt[0]) return;
  int r = list[p];
  int j0 = row_ptr[r], j1 = row_ptr[r + 1];
  float4 a0 = {0.f, 0.f, 0.f, 0.f}, a1 = {0.f, 0.f, 0.f, 0.f};
  float4 a2 = {0.f, 0.f, 0.f, 0.f}, a3 = {0.f, 0.f, 0.f, 0.f};
  int j = j0;
  for (; j + 4 <= j1; j += 4) {
    int2 e0 = edges[j], e1 = edges[j + 1], e2 = edges[j + 2], e3 = edges[j + 3];
    const float4 s0 = *(const float4*)(src + (size_t)e0.x * DDIM + li * 4);
    const float4 s1 = *(const float4*)(src + (size_t)e1.x * DDIM + li * 4);
    const float4 s2 = *(const float4*)(src + (size_t)e2.x * DDIM + li * 4);
    const float4 s3 = *(const float4*)(src + (size_t)e3.x * DDIM + li * 4);
    float v0 = __int_as_float(e0.y), v1 = __int_as_float(e1.y);
    float v2 = __int_as_float(e2.y), v3 = __int_as_float(e3.y);
    a0.x += v0 * s0.x; a0.y += v0 * s0.y; a0.z += v0 * s0.z; a0.w += v0 * s0.w;
    a1.x += v1 * s1.x; a1.y += v1 * s1.y; a1.z += v1 * s1.z; a1.w += v1 * s1.w;
    a2.x += v2 * s2.x; a2.y += v2 * s2.y; a2.z += v2 * s2.z; a2.w += v2 * s2.w;
    a3.x += v3 * s3.x; a3.y += v3 * s3.y; a3.z += v3 * s3.z; a3.w += v3 * s3.w;
  }
  for (; j < j1; ++j) {
    int2 e0 = edges[j];
    const float4 s0 = *(const float4*)(src + (size_t)e0.x * DDIM + li * 4);
    float v0 = __int_as_float(e0.y);
    a0.x += v0 * s0.x; a0.y += v0 * s0.y; a0.z += v0 * s0.z; a0.w += v0 * s0.w;
  }
  float4 o = {a0.x + a1.x + a2.x + a3.x, a0.y + a1.y + a2.y + a3.y,
              a0.z + a1.z + a2.z + a3.z, a0.w + a1.w + a2.w + a3.w};
  *(float4*)(dstc + (size_t)p * DDIM + li * 4) = o;
}

// ---------------------------------------------------------------- seed finish: g=(e0+e1+e2+e3)/4 -> uf/itf col 0
__global__ __launch_bounds__(256) void seed_finish(
    const float* __restrict__ emb, const float* __restrict__ e1,
    const float* __restrict__ e2c, const int* __restrict__ flag,
    const int* __restrict__ row_ptr, const int2* __restrict__ edges,
    const int* __restrict__ users, const int* __restrict__ items,
    float* __restrict__ uf, float* __restrict__ itf) {
  int tid = threadIdx.x;
  int wave = tid >> 6, w = tid & 63, g = w >> 4, li = w & 15;
  int qi = blockIdx.x * 16 + wave * 4 + g;
  int s = (qi < B_C) ? users[qi] : items[qi - B_C] + NU;
  int j0 = row_ptr[s], j1 = row_ptr[s + 1];
  float4 a0 = {0.f, 0.f, 0.f, 0.f}, a1 = {0.f, 0.f, 0.f, 0.f};
  int j = j0;
  for (; j + 2 <= j1; j += 2) {
    int2 e0 = edges[j], e1v = edges[j + 1];
    int p0 = flag[e0.x] - 1; p0 = p0 > 0 ? p0 : 0;
    int p1 = flag[e1v.x] - 1; p1 = p1 > 0 ? p1 : 0;
    const float4 s0 = *(const float4*)(e2c + (size_t)p0 * DDIM + li * 4);
    const float4 s1 = *(const float4*)(e2c + (size_t)p1 * DDIM + li * 4);
    float v0 = __int_as_float(e0.y), v1 = __int_as_float(e1v.y);
    a0.x += v0 * s0.x; a0.y += v0 * s0.y; a0.z += v0 * s0.z; a0.w += v0 * s0.w;
    a1.x += v1 * s1.x; a1.y += v1 * s1.y; a1.z += v1 * s1.z; a1.w += v1 * s1.w;
  }
  if (j < j1) {
    int2 e0 = edges[j];
    int p0 = flag[e0.x] - 1; p0 = p0 > 0 ? p0 : 0;
    const float4 s0 = *(const float4*)(e2c + (size_t)p0 * DDIM + li * 4);
    float v0 = __int_as_float(e0.y);
    a0.x += v0 * s0.x; a0.y += v0 * s0.y; a0.z += v0 * s0.z; a0.w += v0 * s0.w;
  }
  const float4 e0v = *(const float4*)(emb + (size_t)s * DDIM + li * 4);
  const float4 e1r = *(const float4*)(e1 + (size_t)s * DDIM + li * 4);
  int ps = flag[s] - 1; ps = ps > 0 ? ps : 0;
  const float4 e2v = *(const float4*)(e2c + (size_t)ps * DDIM + li * 4);
  float4 o;
  o.x = (e0v.x + e1r.x + e2v.x + a0.x + a1.x) * 0.25f;
  o.y = (e0v.y + e1r.y + e2v.y + a0.y + a1.y) * 0.25f;
  o.z = (e0v.z + e1r.z + e2v.z + a0.z + a1.z) * 0.25f;
  o.w = (e0v.w + e1r.w + e2v.w + a0.w + a1.w) * 0.25f;
  float* row = (qi < B_C) ? uf + (size_t)qi * CDIM : itf + (size_t)(qi - B_C) * CDIM;
  *(float4*)(row + li * 4) = o;
}

// ---------------------------------------------------------------- fused features
__device__ inline void xr4(float4& a) {
  a.x += __shfl_xor(a.x, 16, 64); a.y += __shfl_xor(a.y, 16, 64);
  a.z += __shfl_xor(a.z, 16, 64); a.w += __shfl_xor(a.w, 16, 64);
  a.x += __shfl_xor(a.x, 32, 64); a.y += __shfl_xor(a.y, 32, 64);
  a.z += __shfl_xor(a.z, 32, 64); a.w += __shfl_xor(a.w, 32, 64);
}

__global__ __launch_bounds__(256) void feat_kernel(
    const float* __restrict__ emb, const float* __restrict__ cate_table,
    const int* __restrict__ cates, const int* __restrict__ cate_lens,
    const int* __restrict__ items, const int* __restrict__ ihm,
    const int* __restrict__ ihl, const int* __restrict__ uhm,
    const int* __restrict__ uhl, float* __restrict__ uf,
    float* __restrict__ itf) {
  int tid = threadIdx.x;
  int wave = tid >> 6, w = tid & 63, g = w >> 4, li = w & 15;
  int q = blockIdx.x * 4 + wave;
  if (q < B_C) {
    int b = q;
    int len = ihl[b];
    float4 su = {0.f, 0.f, 0.f, 0.f}, sc = {0.f, 0.f, 0.f, 0.f};
    for (int h = g; h < len; h += 4) {
      int it = ihm[b * HIST_C + h];
      const float4 iv = *(const float4*)(emb + ((size_t)NU + it) * DDIM + li * 4);
      su.x += iv.x; su.y += iv.y; su.z += iv.z; su.w += iv.w;
      int cl = cate_lens[it];
      float4 cs = {0.f, 0.f, 0.f, 0.f};
      for (int c = 0; c < cl; ++c) {
        const float4 cv = *(const float4*)(cate_table + (size_t)cates[it * MC_C + c] * DDIM + li * 4);
        cs.x += cv.x; cs.y += cv.y; cs.z += cv.z; cs.w += cv.w;
      }
      float icl = 1.f / (float)cl;
      sc.x += cs.x * icl; sc.y += cs.y * icl; sc.z += cs.z * icl; sc.w += cs.w * icl;
    }
    xr4(su); xr4(sc);
    float inv = 1.f / (float)len;
    float* urow = uf + (size_t)b * CDIM;
    if (g == 0) {
      float4 o = {su.x * inv, su.y * inv, su.z * inv, su.w * inv};
      *(float4*)(urow + 64 + li * 4) = o;
    } else if (g == 1) {
      float4 o = {sc.x * inv, sc.y * inv, sc.z * inv, sc.w * inv};
      *(float4*)(urow + 128 + li * 4) = o;
    }
  } else {
    int b = q - B_C;
    int it = items[b];
    int cl = cate_lens[it];
    float4 cs = {0.f, 0.f, 0.f, 0.f};
    for (int c = g; c < cl; c += 4) {
      const float4 cv = *(const float4*)(cate_table + (size_t)cates[it * MC_C + c] * DDIM + li * 4);
      cs.x += cv.x; cs.y += cv.y; cs.z += cv.z; cs.w += cv.w;
    }
    int ul = uhl[b];
    float4 hs = {0.f, 0.f, 0.f, 0.f};
    for (int h = g; h < ul; h += 4) {
      const float4 hv = *(const float4*)(emb + (size_t)uhm[b * UHIST_C + h] * DDIM + li * 4);
      hs.x += hv.x; hs.y += hv.y; hs.z += hv.z; hs.w += hv.w;
    }
    xr4(cs); xr4(hs);
    float* irow = itf + (size_t)b * CDIM;
    if (g == 0) {
      float icl = 1.f / (float)cl;
      float4 o = {cs.x * icl, cs.y * icl, cs.z * icl, cs.w * icl};
      *(float4*)(irow + 64 + li * 4) = o;
    } else if (g == 1) {
      float iul = 1.f / (float)ul;
      float4 o = {hs.x * iul, hs.y * iul, hs.z * iul, hs.w * iul};
      *(float4*)(irow + 128 + li * 4) = o;
    }
  }
}

// ---------------------------------------------------------------- layernorm
__global__ __launch_bounds__(64) void ln_kernel(
    const float* __restrict__ uf, const float* __restrict__ itf,
    const float* __restrict__ lnw, const float* __restrict__ lnb,
    float* __restrict__ y) {
  int b = blockIdx.x, p = blockIdx.y, t = threadIdx.x;
  const float* x = ((p < 2) ? uf : itf) + (size_t)b * CDIM;
  float v0 = x[t], v1 = x[t + 64], v2 = x[t + 128];
  float s = v0 + v1 + v2;
#pragma unroll
  for (int off = 32; off; off >>= 1) s += __shfl_down(s, off, 64);
  float mu = __shfl(s, 0, 64) * (1.f / 192.f);
  float d0 = v0 - mu, d1 = v1 - mu, d2 = v2 - mu;
  float q = d0 * d0 + d1 * d1 + d2 * d2;
#pragma unroll
  for (int off = 32; off; off >>= 1) q += __shfl_down(q, off, 64);
  float var = __shfl(q, 0, 64) * (1.f / 192.f);
  float rs = 1.f / sqrtf(var + 1e-5f);
  float* yo = y + ((size_t)p * B_C + b) * CDIM;
  const float* w = lnw + p * CDIM;
  const float* bb = lnb + p * CDIM;
  yo[t]       = d0 * rs * w[t]       + bb[t];
  yo[t + 64]  = d1 * rs * w[t + 64]  + bb[t + 64];
  yo[t + 128] = d2 * rs * w[t + 128] + bb[t + 128];
}

// ---------------------------------------------------------------- GEMM1: h = relu(y@W1 + b1)
__global__ __launch_bounds__(256) void gemm1_kernel(
    const float* __restrict__ y, const float* __restrict__ w1,
    const float* __restrict__ b1, float* __restrict__ h) {
  int p = blockIdx.z;
  const float* A = y + (size_t)p * B_C * CDIM;
  const float* Bm = w1 + (size_t)p * CDIM * IDIM;
  const float* bias = b1 + p * IDIM;
  float* H = h + (size_t)p * B_C * IDIM;
  int r0 = blockIdx.x * 64, c0 = blockIdx.y * 64;
  __shared__ float As[64][68];
  __shared__ float Bs[64][64];
  int tid = threadIdx.x;
  int lr = tid >> 4, lc = (tid & 15) * 4;
  int tx = tid & 15, ty = tid >> 4;
  float acc[4][4] = {};
  for (int k0 = 0; k0 < CDIM; k0 += 64) {
    __syncthreads();
#pragma unroll
    for (int rr = 0; rr < 64; rr += 16) {
      float4 a = *(const float4*)&A[(size_t)(r0 + lr + rr) * CDIM + k0 + lc];
      *(float4*)&As[lr + rr][lc] = a;
      float4 bv = *(const float4*)&Bm[(size_t)(k0 + lr + rr) * IDIM + c0 + lc];
      *(float4*)&Bs[lr + rr][lc] = bv;
    }
    __syncthreads();
#pragma unroll
    for (int k = 0; k < 64; k += 4) {
      float4 a[4], bb[4];
#pragma unroll
      for (int i = 0; i < 4; ++i) a[i] = *(const float4*)&As[ty * 4 + i][k];
#pragma unroll
      for (int kk = 0; kk < 4; ++kk) bb[kk] = *(const float4*)&Bs[k + kk][tx * 4];
#pragma unroll
      for (int i = 0; i < 4; ++i) {
        const float av[4] = {a[i].x, a[i].y, a[i].z, a[i].w};
#pragma unroll
        for (int kk = 0; kk < 4; ++kk) {
          acc[i][0] += av[kk] * bb[kk].x;
          acc[i][1] += av[kk] * bb[kk].y;
          acc[i][2] += av[kk] * bb[kk].z;
          acc[i][3] += av[kk] * bb[kk].w;
        }
      }
    }
  }
  int c = c0 + tx * 4;
#pragma unroll
  for (int i = 0; i < 4; ++i) {
    int row = r0 + ty * 4 + i;
    float4 o;
    o.x = fmaxf(acc[i][0] + bias[c + 0], 0.f);
    o.y = fmaxf(acc[i][1] + bias[c + 1], 0.f);
    o.z = fmaxf(acc[i][2] + bias[c + 2], 0.f);
    o.w = fmaxf(acc[i][3] + bias[c + 3], 0.f);
    *(float4*)&H[(size_t)row * IDIM + c] = o;
  }
}

// ---------------------------------------------------------------- GEMM2: z = sum_i h_i@W2_i + b2s + 2x
__global__ __launch_bounds__(256) void gemm2_kernel(
    const float* __restrict__ h, const float* __restrict__ w2,
    const float* __restrict__ b2, const float* __restrict__ uf,
    const float* __restrict__ itf, float* __restrict__ zu, float* __restrict__ zi) {
  int s = blockIdx.z;
  const float* X = s ? itf : uf;
  float* Z = s ? zi : zu;
  int r0 = blockIdx.x * 64, c0 = blockIdx.y * 64;
  __shared__ float As[64][68];
  __shared__ float Bs[64][64];
  int tid = threadIdx.x;
  int lr = tid >> 4, lc = (tid & 15) * 4;
  int tx = tid & 15, ty = tid >> 4;
  float acc[4][4] = {};
  for (int pi = 0; pi < 2; ++pi) {
    int p = s * 2 + pi;
    const float* A = h + (size_t)p * B_C * IDIM;
    const float* Bm = w2 + (size_t)p * IDIM * CDIM;
    for (int k0 = 0; k0 < IDIM; k0 += 64) {
      __syncthreads();
#pragma unroll
      for (int rr = 0; rr < 64; rr += 16) {
        float4 a = *(const float4*)&A[(size_t)(r0 + lr + rr) * IDIM + k0 + lc];
        *(float4*)&As[lr + rr][lc] = a;
        float4 bv = *(const float4*)&Bm[(size_t)(k0 + lr + rr) * CDIM + c0 + lc];
        *(float4*)&Bs[lr + rr][lc] = bv;
      }
      __syncthreads();
#pragma unroll
      for (int k = 0; k < 64; k += 4) {
        float4 a[4], bb[4];
#pragma unroll
        for (int i = 0; i < 4; ++i) a[i] = *(const float4*)&As[ty * 4 + i][k];
#pragma unroll
        for (int kk = 0; kk < 4; ++kk) bb[kk] = *(const float4*)&Bs[k + kk][tx * 4];
#pragma unroll
        for (int i = 0; i < 4; ++i) {
          const float av[4] = {a[i].x, a[i].y, a[i].z, a[i].w};
#pragma unroll
          for (int kk = 0; kk < 4; ++kk) {
            acc[i][0] += av[kk] * bb[kk].x;
            acc[i][1] += av[kk] * bb[kk].y;
            acc[i][2] += av[kk] * bb[kk].z;
            acc[i][3] += av[kk] * bb[kk].w;
          }
        }
      }
    }
  }
  int c = c0 + tx * 4;
  float bs0 = b2[(s * 2) * CDIM + c + 0] + b2[(s * 2 + 1) * CDIM + c + 0];
  float bs1 = b2[(s * 2) * CDIM + c + 1] + b2[(s * 2 + 1) * CDIM + c + 1];
  float bs2 = b2[(s * 2) * CDIM + c + 2] + b2[(s * 2 + 1) * CDIM + c + 2];
  float bs3 = b2[(s * 2) * CDIM + c + 3] + b2[(s * 2 + 1) * CDIM + c + 3];
#pragma unroll
  for (int i = 0; i < 4; ++i) {
    int row = r0 + ty * 4 + i;
    float4 x4 = *(const float4*)&X[(size_t)row * CDIM + c];
    float4 o;
    o.x = acc[i][0] + bs0 + 2.f * x4.x;
    o.y = acc[i][1] + bs1 + 2.f * x4.y;
    o.z = acc[i][2] + bs2 + 2.f * x4.z;
    o.w = acc[i][3] + bs3 + 2.f * x4.w;
    *(float4*)&Z[(size_t)row * CDIM + c] = o;
  }
}

// ---------------------------------------------------------------- final L2 normalize
__global__ __launch_bounds__(64) void norm_kernel(
    const float* __restrict__ zu, const float* __restrict__ zi,
    float* __restrict__ out) {
  int b = blockIdx.x, s = blockIdx.y, t = threadIdx.x;
  const float* z = (s ? zi : zu) + (size_t)b * CDIM;
  float v0 = z[t], v1 = z[t + 64], v2 = z[t + 128];
  float q = v0 * v0 + v1 * v1 + v2 * v2;
#pragma unroll
  for (int off = 32; off; off >>= 1) q += __shfl_down(q, off, 64);
  float n = sqrtf(__shfl(q, 0, 64));
  float inv = 1.f / fmaxf(n, 1e-12f);
  float* o = out + (size_t)s * B_C * CDIM + (size_t)b * CDIM;
  o[t] = v0 * inv;
  o[t + 64] = v1 * inv;
  o[t + 128] = v2 * inv;
}

// ---------------------------------------------------------------- launch
extern "C" void kernel_launch(void* const* d_in, const int* in_sizes, int n_in,
                              void* d_out, int out_size, void* d_ws, size_t ws_size,
                              hipStream_t stream) {
  const float* emb   = (const float*)d_in[0];
  const float* cate  = (const float*)d_in[1];
  const float* avals = (const float*)d_in[2];
  const float* lnw   = (const float*)d_in[3];
  const float* lnb   = (const float*)d_in[4];
  const float* w1    = (const float*)d_in[5];
  const float* b1    = (const float*)d_in[6];
  const float* w2    = (const float*)d_in[7];
  const float* b2    = (const float*)d_in[8];
  const int* arows   = (const int*)d_in[9];
  const int* acols   = (const int*)d_in[10];
  const int* cates_  = (const int*)d_in[11];
  const int* clens   = (const int*)d_in[12];
  const int* users   = (const int*)d_in[13];
  const int* items   = (const int*)d_in[14];
  const int* ihm     = (const int*)d_in[15];
  const int* ihl     = (const int*)d_in[16];
  const int* uhm     = (const int*)d_in[17];
  const int* uhl     = (const int*)d_in[18];
  float* out = (float*)d_out;

  float* W = (float*)d_ws;
  float* e1      = W;                         // 9,600,000 f
  float* e2c     = W + 9600000;               // 6,160,384 f (MAXF*64) -> 15,760,384
  int2*  edges   = (int2*)(W + 15760384);     // 2,400,000 int2 -> 20,560,384
  int*   row_ptr = (int*)(W + 20560384);      // 150,532 i -> 20,710,916
  int*   deg     = (int*)(W + 20710916);      // 150,528 i -> 20,861,444 (deg|flag|cnt one memset)
  int*   flag    = (int*)(W + 20861444);      // 150,528 i -> 21,011,972 (padded for scan)
  int*   cnt     = (int*)(W + 21011972);      // 64 i -> 21,012,036
  int*   list    = (int*)(W + 21012036);      // 96,256 i -> 21,108,292
  int*   bsums   = (int*)(W + 21108292);      // 256 i -> 21,108,548
  int*   bsums2  = (int*)(W + 21108548);      // 256 i -> 21,108,804
  float* uf      = W + 21108804;              // 786,432 f -> 21,895,236
  float* itf     = W + 21895236;              // 786,432 f -> 22,681,668 (90.7 MB)
  // pos aliases e2c (dead until spmm_gather4_masked; csr_fill consumes pos first)
  int*   pos = (int*)e2c;                     // 2,400,000 i (9.6 MB of 24.6 MB)
  // post-GNN reuse:
  float* y  = e1;                             // [4][B][192] = 3,145,728 f
  float* h  = e1 + 3145728;                   // [4][B][384] = 6,291,456 f
  float* zu = e2c;                            // 786,432 f
  float* zi = e2c + 786432;                   // 786,432 f

  // ---- CSR build: rank (atomic, 4 indep/thread) -> scans -> atomic-free fill
  (void)hipMemsetAsync(deg, 0, (150528 + 150528 + 64) * sizeof(int), stream);
  rank_kernel<<<(NNZ_C + 1023) / 1024, 256, 0, stream>>>(arows, deg, pos);
  scan_reduce<<<SCAN_B, 1024, 0, stream>>>(deg, bsums);
  scan_final<<<SCAN_B, 1024, 0, stream>>>(deg, bsums, row_ptr);
  csr_fill<<<(NNZ_C + 1023) / 1024, 256, 0, stream>>>(arows, acols, avals, row_ptr, pos, edges);

  // ---- frontier = seeds + N(seeds); deterministic scan compaction
  mark_kernel<<<(2 * B_C + 255) / 256, 256, 0, stream>>>(users, items, row_ptr, edges, flag);
  scan_reduce<<<SCAN_B, 1024, 0, stream>>>(flag, bsums2);
  compact_scan<<<SCAN_B, 1024, 0, stream>>>(flag, bsums2, list, cnt);

  // ---- GNN: e1 full gather; e2 masked+compacted; e3 fused into seed_finish
  spmm_gather4<<<NN / 16, 256, 0, stream>>>(emb, e1, row_ptr, edges);
  spmm_gather4_masked<<<MAXF / 16, 256, 0, stream>>>(e1, e2c, row_ptr, edges, list, cnt);
  seed_finish<<<(2 * B_C) / 16, 256, 0, stream>>>(emb, e1, e2c, flag, row_ptr,
                                                  edges, users, items, uf, itf);

  // ---- features (cols 64..192 of uf/itf)
  feat_kernel<<<(2 * B_C) / 4, 256, 0, stream>>>(emb, cate, cates_, clens, items,
                                                 ihm, ihl, uhm, uhl, uf, itf);

  // ---- MLP blocks
  ln_kernel<<<dim3(B_C, 4), 64, 0, stream>>>(uf, itf, lnw, lnb, y);
  gemm1_kernel<<<dim3(B_C / 64, IDIM / 64, 4), 256, 0, stream>>>(y, w1, b1, h);
  gemm2_kernel<<<dim3(B_C / 64, CDIM / 64, 2), 256, 0, stream>>>(h, w2, b2, uf, itf, zu, zi);
  norm_kernel<<<dim3(B_C, 2), 64, 0, stream>>>(zu, zi, out);
}

// Round 9
// 580.452 us; speedup vs baseline: 1.2584x; 1.0103x over previous
//
#include <hip/hip_runtime.h>
#include <hip/hip_bf16.h>
#include <cstdint>
#include <cstddef>

#define NU      100000
#define NN      150000
#define DDIM    64
#define NNZ_C   2400000
#define B_C     4096
#define HIST_C  50
#define UHIST_C 30
#define MC_C    5
#define CDIM    192
#define IDIM    384
#define SCAN_B  147
#define SCAN_N  (SCAN_B * 1024)   // 150528 >= NN, padded for scan
#define MAXF    96256             // frontier slots (expected ~89.1K); multiple of 16

// ---------------------------------------------------------------- CSR build
// rank_kernel: deg histogram AND intra-row rank in one pass.
// 8 independent atomics per thread (strided for coalesced rows[] reads).
__global__ __launch_bounds__(256) void rank_kernel(
    const int* __restrict__ rows, int* __restrict__ deg, int* __restrict__ pos) {
  int base = blockIdx.x * 2048 + threadIdx.x;
#pragma unroll
  for (int k = 0; k < 8; ++k) {
    int e = base + k * 256;
    if (e < NNZ_C) pos[e] = atomicAdd(&deg[rows[e]], 1);
  }
}

// generic block-sum over an array of SCAN_N ints
__global__ __launch_bounds__(1024) void scan_reduce(
    const int* __restrict__ arr, int* __restrict__ bsums) {
  __shared__ int s[1024];
  int t = threadIdx.x;
  s[t] = arr[blockIdx.x * 1024 + t];
  __syncthreads();
  for (int off = 512; off; off >>= 1) {
    if (t < off) s[t] += s[t + off];
    __syncthreads();
  }
  if (t == 0) bsums[blockIdx.x] = s[0];
}

// fused: in-block prefix over bsums + local scan; writes row_ptr
__global__ __launch_bounds__(1024) void scan_final(
    const int* __restrict__ deg, const int* __restrict__ bsums,
    int* __restrict__ row_ptr) {
  __shared__ int pre[1024];
  __shared__ int s[1024];
  int t = threadIdx.x;
  pre[t] = (t < (int)blockIdx.x) ? bsums[t] : 0;
  __syncthreads();
  for (int off = 512; off; off >>= 1) {
    if (t < off) pre[t] += pre[t + off];
    __syncthreads();
  }
  int base = pre[0];
  __syncthreads();
  int i = blockIdx.x * 1024 + t;
  int v = deg[i];
  s[t] = v;
  __syncthreads();
  for (int off = 1; off < 1024; off <<= 1) {
    int u = (t >= off) ? s[t - off] : 0;
    __syncthreads();
    s[t] += u;
    __syncthreads();
  }
  row_ptr[i] = base + s[t] - v;
  if (i == SCAN_N - 1) row_ptr[SCAN_N] = base + s[t];
}

// atomic-free fill: position = row_ptr[r] + precomputed rank. Pure scatter,
// 8 independent stores per thread.
__global__ __launch_bounds__(256) void csr_fill(
    const int* __restrict__ rows, const int* __restrict__ cols,
    const float* __restrict__ vals, const int* __restrict__ row_ptr,
    const int* __restrict__ pos, int2* __restrict__ edges) {
  int base = blockIdx.x * 2048 + threadIdx.x;
#pragma unroll
  for (int k = 0; k < 8; ++k) {
    int e = base + k * 256;
    if (e < NNZ_C) {
      int r = rows[e];
      edges[row_ptr[r] + pos[e]] = make_int2(cols[e], __float_as_int(vals[e]));
    }
  }
}

// ---------------------------------------------------------------- frontier mark + deterministic compact
__global__ __launch_bounds__(256) void mark_kernel(
    const int* __restrict__ users, const int* __restrict__ items,
    const int* __restrict__ row_ptr, const int2* __restrict__ edges,
    int* __restrict__ flag) {
  int t = blockIdx.x * 256 + threadIdx.x;
  if (t >= 2 * B_C) return;
  int s = (t < B_C) ? users[t] : items[t - B_C] + NU;
  flag[s] = 1;
  int j0 = row_ptr[s], j1 = row_ptr[s + 1];
  for (int j = j0; j < j1; ++j) flag[edges[j].x] = 1;
}

// deterministic compaction: slot = exclusive prefix sum of flag (0/1)
__global__ __launch_bounds__(1024) void compact_scan(
    int* __restrict__ flag, const int* __restrict__ bsums2,
    int* __restrict__ list, int* __restrict__ cnt) {
  __shared__ int pre[1024];
  __shared__ int s[1024];
  int t = threadIdx.x;
  pre[t] = (t < (int)blockIdx.x) ? bsums2[t] : 0;
  __syncthreads();
  for (int off = 512; off; off >>= 1) {
    if (t < off) pre[t] += pre[t + off];
    __syncthreads();
  }
  int base = pre[0];
  __syncthreads();
  int i = blockIdx.x * 1024 + t;
  int v = flag[i];
  s[t] = v;
  __syncthreads();
  for (int off = 1; off < 1024; off <<= 1) {
    int u = (t >= off) ? s[t - off] : 0;
    __syncthreads();
    s[t] += u;
    __syncthreads();
  }
  int slot = base + s[t] - v;  // exclusive
  if (v) {
    if (slot < MAXF) { list[slot] = i; flag[i] = slot + 1; }
    else flag[i] = 0;
  }
  if (i == SCAN_N - 1) {
    int tot = base + s[t];
    cnt[0] = (tot < MAXF) ? tot : MAXF;
  }
}

// ---------------------------------------------------------------- layer-1 gather SpMM
// 4 rows/wave, 16 lanes x float4 per row, unroll x8 -> 32 gather chains/wave
__global__ __launch_bounds__(256) void spmm_gather4(
    const float* __restrict__ src, float* __restrict__ dst,
    const int* __restrict__ row_ptr, const int2* __restrict__ edges) {
  int tid = threadIdx.x;
  int wave = tid >> 6, w = tid & 63, g = w >> 4, li = w & 15;
  int r = blockIdx.x * 16 + wave * 4 + g;
  int j0 = row_ptr[r], j1 = row_ptr[r + 1];
  float4 a0 = {0.f, 0.f, 0.f, 0.f}, a1 = {0.f, 0.f, 0.f, 0.f};
  float4 a2 = {0.f, 0.f, 0.f, 0.f}, a3 = {0.f, 0.f, 0.f, 0.f};
  int j = j0;
  for (; j + 8 <= j1; j += 8) {
    int2 e0 = edges[j], e1 = edges[j + 1], e2 = edges[j + 2], e3 = edges[j + 3];
    int2 e4 = edges[j + 4], e5 = edges[j + 5], e6 = edges[j + 6], e7 = edges[j + 7];
    const float4 s0 = *(const float4*)(src + (size_t)e0.x * DDIM + li * 4);
    const float4 s1 = *(const float4*)(src + (size_t)e1.x * DDIM + li * 4);
    const float4 s2 = *(const float4*)(src + (size_t)e2.x * DDIM + li * 4);
    const float4 s3 = *(const float4*)(src + (size_t)e3.x * DDIM + li * 4);
    const float4 s4 = *(const float4*)(src + (size_t)e4.x * DDIM + li * 4);
    const float4 s5 = *(const float4*)(src + (size_t)e5.x * DDIM + li * 4);
    const float4 s6 = *(const float4*)(src + (size_t)e6.x * DDIM + li * 4);
    const float4 s7 = *(const float4*)(src + (size_t)e7.x * DDIM + li * 4);
    float v0 = __int_as_float(e0.y), v1 = __int_as_float(e1.y);
    float v2 = __int_as_float(e2.y), v3 = __int_as_float(e3.y);
    float v4 = __int_as_float(e4.y), v5 = __int_as_float(e5.y);
    float v6 = __int_as_float(e6.y), v7 = __int_as_float(e7.y);
    a0.x += v0 * s0.x; a0.y += v0 * s0.y; a0.z += v0 * s0.z; a0.w += v0 * s0.w;
    a1.x += v1 * s1.x; a1.y += v1 * s1.y; a1.z += v1 * s1.z; a1.w += v1 * s1.w;
    a2.x += v2 * s2.x; a2.y += v2 * s2.y; a2.z += v2 * s2.z; a2.w += v2 * s2.w;
    a3.x += v3 * s3.x; a3.y += v3 * s3.y; a3.z += v3 * s3.z; a3.w += v3 * s3.w;
    a0.x += v4 * s4.x; a0.y += v4 * s4.y; a0.z += v4 * s4.z; a0.w += v4 * s4.w;
    a1.x += v5 * s5.x; a1.y += v5 * s5.y; a1.z += v5 * s5.z; a1.w += v5 * s5.w;
    a2.x += v6 * s6.x; a2.y += v6 * s6.y; a2.z += v6 * s6.z; a2.w += v6 * s6.w;
    a3.x += v7 * s7.x; a3.y += v7 * s7.y; a3.z += v7 * s7.z; a3.w += v7 * s7.w;
  }
  for (; j + 2 <= j1; j += 2) {
    int2 e0 = edges[j], e1 = edges[j + 1];
    const float4 s0 = *(const float4*)(src + (size_t)e0.x * DDIM + li * 4);
    const float4 s1 = *(const float4*)(src + (size_t)e1.x * DDIM + li * 4);
    float v0 = __int_as_float(e0.y), v1 = __int_as_float(e1.y);
    a0.x += v0 * s0.x; a0.y += v0 * s0.y; a0.z += v0 * s0.z; a0.w += v0 * s0.w;
    a1.x += v1 * s1.x; a1.y += v1 * s1.y; a1.z += v1 * s1.z; a1.w += v1 * s1.w;
  }
  if (j < j1) {
    int2 e0 = edges[j];
    const float4 s0 = *(const float4*)(src + (size_t)e0.x * DDIM + li * 4);
    float v0 = __int_as_float(e0.y);
    a0.x += v0 * s0.x; a0.y += v0 * s0.y; a0.z += v0 * s0.z; a0.w += v0 * s0.w;
  }
  float4 o = {a0.x + a1.x + a2.x + a3.x, a0.y + a1.y + a2.y + a3.y,
              a0.z + a1.z + a2.z + a3.z, a0.w + a1.w + a2.w + a3.w};
  *(float4*)(dst + (size_t)r * DDIM + li * 4) = o;
}

// ---------------------------------------------------------------- masked layer-2 (compacted output)
__global__ __launch_bounds__(256) void spmm_gather4_masked(
    const float* __restrict__ src, float* __restrict__ dstc,
    const int* __restrict__ row_ptr, const int2* __restrict__ edges,
    const int* __restrict__ list, const int* __restrict__ cnt) {
  int tid = threadIdx.x;
  int wave = tid >> 6, w = tid & 63, g = w >> 4, li = w & 15;
  int p = blockIdx.x * 16 + wave * 4 + g;
  if (p >= cnt[0]) return;
  int r = list[p];
  int j0 = row_ptr[r], j1 = row_ptr[r + 1];
  float4 a0 = {0.f, 0.f, 0.f, 0.f}, a1 = {0.f, 0.f, 0.f, 0.f};
  float4 a2 = {0.f, 0.f, 0.f, 0.f}, a3 = {0.f, 0.f, 0.f, 0.f};
  int j = j0;
  for (; j + 8 <= j1; j += 8) {
    int2 e0 = edges[j], e1 = edges[j + 1], e2 = edges[j + 2], e3 = edges[j + 3];
    int2 e4 = edges[j + 4], e5 = edges[j + 5], e6 = edges[j + 6], e7 = edges[j + 7];
    const float4 s0 = *(const float4*)(src + (size_t)e0.x * DDIM + li * 4);
    const float4 s1 = *(const float4*)(src + (size_t)e1.x * DDIM + li * 4);
    const float4 s2 = *(const float4*)(src + (size_t)e2.x * DDIM + li * 4);
    const float4 s3 = *(const float4*)(src + (size_t)e3.x * DDIM + li * 4);
    const float4 s4 = *(const float4*)(src + (size_t)e4.x * DDIM + li * 4);
    const float4 s5 = *(const float4*)(src + (size_t)e5.x * DDIM + li * 4);
    const float4 s6 = *(const float4*)(src + (size_t)e6.x * DDIM + li * 4);
    const float4 s7 = *(const float4*)(src + (size_t)e7.x * DDIM + li * 4);
    float v0 = __int_as_float(e0.y), v1 = __int_as_float(e1.y);
    float v2 = __int_as_float(e2.y), v3 = __int_as_float(e3.y);
    float v4 = __int_as_float(e4.y), v5 = __int_as_float(e5.y);
    float v6 = __int_as_float(e6.y), v7 = __int_as_float(e7.y);
    a0.x += v0 * s0.x; a0.y += v0 * s0.y; a0.z += v0 * s0.z; a0.w += v0 * s0.w;
    a1.x += v1 * s1.x; a1.y += v1 * s1.y; a1.z += v1 * s1.z; a1.w += v1 * s1.w;
    a2.x += v2 * s2.x; a2.y += v2 * s2.y; a2.z += v2 * s2.z; a2.w += v2 * s2.w;
    a3.x += v3 * s3.x; a3.y += v3 * s3.y; a3.z += v3 * s3.z; a3.w += v3 * s3.w;
    a0.x += v4 * s4.x; a0.y += v4 * s4.y; a0.z += v4 * s4.z; a0.w += v4 * s4.w;
    a1.x += v5 * s5.x; a1.y += v5 * s5.y; a1.z += v5 * s5.z; a1.w += v5 * s5.w;
    a2.x += v6 * s6.x; a2.y += v6 * s6.y; a2.z += v6 * s6.z; a2.w += v6 * s6.w;
    a3.x += v7 * s7.x; a3.y += v7 * s7.y; a3.z += v7 * s7.z; a3.w += v7 * s7.w;
  }
  for (; j + 2 <= j1; j += 2) {
    int2 e0 = edges[j], e1 = edges[j + 1];
    const float4 s0 = *(const float4*)(src + (size_t)e0.x * DDIM + li * 4);
    const float4 s1 = *(const float4*)(src + (size_t)e1.x * DDIM + li * 4);
    float v0 = __int_as_float(e0.y), v1 = __int_as_float(e1.y);
    a0.x += v0 * s0.x; a0.y += v0 * s0.y; a0.z += v0 * s0.z; a0.w += v0 * s0.w;
    a1.x += v1 * s1.x; a1.y += v1 * s1.y; a1.z += v1 * s1.z; a1.w += v1 * s1.w;
  }
  if (j < j1) {
    int2 e0 = edges[j];
    const float4 s0 = *(const float4*)(src + (size_t)e0.x * DDIM + li * 4);
    float v0 = __int_as_float(e0.y);
    a0.x += v0 * s0.x; a0.y += v0 * s0.y; a0.z += v0 * s0.z; a0.w += v0 * s0.w;
  }
  float4 o = {a0.x + a1.x + a2.x + a3.x, a0.y + a1.y + a2.y + a3.y,
              a0.z + a1.z + a2.z + a3.z, a0.w + a1.w + a2.w + a3.w};
  *(float4*)(dstc + (size_t)p * DDIM + li * 4) = o;
}

// ---------------------------------------------------------------- seed finish: g=(e0+e1+e2+e3)/4 -> uf/itf col 0
__global__ __launch_bounds__(256) void seed_finish(
    const float* __restrict__ emb, const float* __restrict__ e1,
    const float* __restrict__ e2c, const int* __restrict__ flag,
    const int* __restrict__ row_ptr, const int2* __restrict__ edges,
    const int* __restrict__ users, const int* __restrict__ items,
    float* __restrict__ uf, float* __restrict__ itf) {
  int tid = threadIdx.x;
  int wave = tid >> 6, w = tid & 63, g = w >> 4, li = w & 15;
  int qi = blockIdx.x * 16 + wave * 4 + g;
  int s = (qi < B_C) ? users[qi] : items[qi - B_C] + NU;
  int j0 = row_ptr[s], j1 = row_ptr[s + 1];
  float4 a0 = {0.f, 0.f, 0.f, 0.f}, a1 = {0.f, 0.f, 0.f, 0.f};
  float4 a2 = {0.f, 0.f, 0.f, 0.f}, a3 = {0.f, 0.f, 0.f, 0.f};
  int j = j0;
  for (; j + 4 <= j1; j += 4) {
    int2 e0 = edges[j], e1v = edges[j + 1], e2v = edges[j + 2], e3v = edges[j + 3];
    int p0 = flag[e0.x] - 1;  p0 = p0 > 0 ? p0 : 0;
    int p1 = flag[e1v.x] - 1; p1 = p1 > 0 ? p1 : 0;
    int p2 = flag[e2v.x] - 1; p2 = p2 > 0 ? p2 : 0;
    int p3 = flag[e3v.x] - 1; p3 = p3 > 0 ? p3 : 0;
    const float4 s0 = *(const float4*)(e2c + (size_t)p0 * DDIM + li * 4);
    const float4 s1 = *(const float4*)(e2c + (size_t)p1 * DDIM + li * 4);
    const float4 s2 = *(const float4*)(e2c + (size_t)p2 * DDIM + li * 4);
    const float4 s3 = *(const float4*)(e2c + (size_t)p3 * DDIM + li * 4);
    float v0 = __int_as_float(e0.y), v1 = __int_as_float(e1v.y);
    float v2 = __int_as_float(e2v.y), v3 = __int_as_float(e3v.y);
    a0.x += v0 * s0.x; a0.y += v0 * s0.y; a0.z += v0 * s0.z; a0.w += v0 * s0.w;
    a1.x += v1 * s1.x; a1.y += v1 * s1.y; a1.z += v1 * s1.z; a1.w += v1 * s1.w;
    a2.x += v2 * s2.x; a2.y += v2 * s2.y; a2.z += v2 * s2.z; a2.w += v2 * s2.w;
    a3.x += v3 * s3.x; a3.y += v3 * s3.y; a3.z += v3 * s3.z; a3.w += v3 * s3.w;
  }
  for (; j < j1; ++j) {
    int2 e0 = edges[j];
    int p0 = flag[e0.x] - 1; p0 = p0 > 0 ? p0 : 0;
    const float4 s0 = *(const float4*)(e2c + (size_t)p0 * DDIM + li * 4);
    float v0 = __int_as_float(e0.y);
    a0.x += v0 * s0.x; a0.y += v0 * s0.y; a0.z += v0 * s0.z; a0.w += v0 * s0.w;
  }
  const float4 e0v = *(const float4*)(emb + (size_t)s * DDIM + li * 4);
  const float4 e1r = *(const float4*)(e1 + (size_t)s * DDIM + li * 4);
  int ps = flag[s] - 1; ps = ps > 0 ? ps : 0;
  const float4 e2v = *(const float4*)(e2c + (size_t)ps * DDIM + li * 4);
  float4 o;
  o.x = (e0v.x + e1r.x + e2v.x + a0.x + a1.x + a2.x + a3.x) * 0.25f;
  o.y = (e0v.y + e1r.y + e2v.y + a0.y + a1.y + a2.y + a3.y) * 0.25f;
  o.z = (e0v.z + e1r.z + e2v.z + a0.z + a1.z + a2.z + a3.z) * 0.25f;
  o.w = (e0v.w + e1r.w + e2v.w + a0.w + a1.w + a2.w + a3.w) * 0.25f;
  float* row = (qi < B_C) ? uf + (size_t)qi * CDIM : itf + (size_t)(qi - B_C) * CDIM;
  *(float4*)(row + li * 4) = o;
}

// ---------------------------------------------------------------- fused features
__device__ inline void xr4(float4& a) {
  a.x += __shfl_xor(a.x, 16, 64); a.y += __shfl_xor(a.y, 16, 64);
  a.z += __shfl_xor(a.z, 16, 64); a.w += __shfl_xor(a.w, 16, 64);
  a.x += __shfl_xor(a.x, 32, 64); a.y += __shfl_xor(a.y, 32, 64);
  a.z += __shfl_xor(a.z, 32, 64); a.w += __shfl_xor(a.w, 32, 64);
}

__global__ __launch_bounds__(256) void feat_kernel(
    const float* __restrict__ emb, const float* __restrict__ cate_table,
    const int* __restrict__ cates, const int* __restrict__ cate_lens,
    const int* __restrict__ items, const int* __restrict__ ihm,
    const int* __restrict__ ihl, const int* __restrict__ uhm,
    const int* __restrict__ uhl, float* __restrict__ uf,
    float* __restrict__ itf) {
  int tid = threadIdx.x;
  int wave = tid >> 6, w = tid & 63, g = w >> 4, li = w & 15;
  int q = blockIdx.x * 4 + wave;
  if (q < B_C) {
    int b = q;
    int len = ihl[b];
    float4 su = {0.f, 0.f, 0.f, 0.f}, sc = {0.f, 0.f, 0.f, 0.f};
    for (int h = g; h < len; h += 4) {
      int it = ihm[b * HIST_C + h];
      const float4 iv = *(const float4*)(emb + ((size_t)NU + it) * DDIM + li * 4);
      su.x += iv.x; su.y += iv.y; su.z += iv.z; su.w += iv.w;
      int cl = cate_lens[it];
      float4 cs = {0.f, 0.f, 0.f, 0.f};
      for (int c = 0; c < cl; ++c) {
        const float4 cv = *(const float4*)(cate_table + (size_t)cates[it * MC_C + c] * DDIM + li * 4);
        cs.x += cv.x; cs.y += cv.y; cs.z += cv.z; cs.w += cv.w;
      }
      float icl = 1.f / (float)cl;
      sc.x += cs.x * icl; sc.y += cs.y * icl; sc.z += cs.z * icl; sc.w += cs.w * icl;
    }
    xr4(su); xr4(sc);
    float inv = 1.f / (float)len;
    float* urow = uf + (size_t)b * CDIM;
    if (g == 0) {
      float4 o = {su.x * inv, su.y * inv, su.z * inv, su.w * inv};
      *(float4*)(urow + 64 + li * 4) = o;
    } else if (g == 1) {
      float4 o = {sc.x * inv, sc.y * inv, sc.z * inv, sc.w * inv};
      *(float4*)(urow + 128 + li * 4) = o;
    }
  } else {
    int b = q - B_C;
    int it = items[b];
    int cl = cate_lens[it];
    float4 cs = {0.f, 0.f, 0.f, 0.f};
    for (int c = g; c < cl; c += 4) {
      const float4 cv = *(const float4*)(cate_table + (size_t)cates[it * MC_C + c] * DDIM + li * 4);
      cs.x += cv.x; cs.y += cv.y; cs.z += cv.z; cs.w += cv.w;
    }
    int ul = uhl[b];
    float4 hs = {0.f, 0.f, 0.f, 0.f};
    for (int h = g; h < ul; h += 4) {
      const float4 hv = *(const float4*)(emb + (size_t)uhm[b * UHIST_C + h] * DDIM + li * 4);
      hs.x += hv.x; hs.y += hv.y; hs.z += hv.z; hs.w += hv.w;
    }
    xr4(cs); xr4(hs);
    float* irow = itf + (size_t)b * CDIM;
    if (g == 0) {
      float icl = 1.f / (float)cl;
      float4 o = {cs.x * icl, cs.y * icl, cs.z * icl, cs.w * icl};
      *(float4*)(irow + 64 + li * 4) = o;
    } else if (g == 1) {
      float iul = 1.f / (float)ul;
      float4 o = {hs.x * iul, hs.y * iul, hs.z * iul, hs.w * iul};
      *(float4*)(irow + 128 + li * 4) = o;
    }
  }
}

// ---------------------------------------------------------------- layernorm
__global__ __launch_bounds__(64) void ln_kernel(
    const float* __restrict__ uf, const float* __restrict__ itf,
    const float* __restrict__ lnw, const float* __restrict__ lnb,
    float* __restrict__ y) {
  int b = blockIdx.x, p = blockIdx.y, t = threadIdx.x;
  const float* x = ((p < 2) ? uf : itf) + (size_t)b * CDIM;
  float v0 = x[t], v1 = x[t + 64], v2 = x[t + 128];
  float s = v0 + v1 + v2;
#pragma unroll
  for (int off = 32; off; off >>= 1) s += __shfl_down(s, off, 64);
  float mu = __shfl(s, 0, 64) * (1.f / 192.f);
  float d0 = v0 - mu, d1 = v1 - mu, d2 = v2 - mu;
  float q = d0 * d0 + d1 * d1 + d2 * d2;
#pragma unroll
  for (int off = 32; off; off >>= 1) q += __shfl_down(q, off, 64);
  float var = __shfl(q, 0, 64) * (1.f / 192.f);
  float rs = 1.f / sqrtf(var + 1e-5f);
  float* yo = y + ((size_t)p * B_C + b) * CDIM;
  const float* w = lnw + p * CDIM;
  const float* bb = lnb + p * CDIM;
  yo[t]       = d0 * rs * w[t]       + bb[t];
  yo[t + 64]  = d1 * rs * w[t + 64]  + bb[t + 64];
  yo[t + 128] = d2 * rs * w[t + 128] + bb[t + 128];
}

// ---------------------------------------------------------------- GEMM1: h = relu(y@W1 + b1)
__global__ __launch_bounds__(256) void gemm1_kernel(
    const float* __restrict__ y, const float* __restrict__ w1,
    const float* __restrict__ b1, float* __restrict__ h) {
  int p = blockIdx.z;
  const float* A = y + (size_t)p * B_C * CDIM;
  const float* Bm = w1 + (size_t)p * CDIM * IDIM;
  const float* bias = b1 + p * IDIM;
  float* H = h + (size_t)p * B_C * IDIM;
  int r0 = blockIdx.x * 64, c0 = blockIdx.y * 64;
  __shared__ float As[64][68];
  __shared__ float Bs[64][64];
  int tid = threadIdx.x;
  int lr = tid >> 4, lc = (tid & 15) * 4;
  int tx = tid & 15, ty = tid >> 4;
  float acc[4][4] = {};
  for (int k0 = 0; k0 < CDIM; k0 += 64) {
    __syncthreads();
#pragma unroll
    for (int rr = 0; rr < 64; rr += 16) {
      float4 a = *(const float4*)&A[(size_t)(r0 + lr + rr) * CDIM + k0 + lc];
      *(float4*)&As[lr + rr][lc] = a;
      float4 bv = *(const float4*)&Bm[(size_t)(k0 + lr + rr) * IDIM + c0 + lc];
      *(float4*)&Bs[lr + rr][lc] = bv;
    }
    __syncthreads();
#pragma unroll
    for (int k = 0; k < 64; k += 4) {
      float4 a[4], bb[4];
#pragma unroll
      for (int i = 0; i < 4; ++i) a[i] = *(const float4*)&As[ty * 4 + i][k];
#pragma unroll
      for (int kk = 0; kk < 4; ++kk) bb[kk] = *(const float4*)&Bs[k + kk][tx * 4];
#pragma unroll
      for (int i = 0; i < 4; ++i) {
        const float av[4] = {a[i].x, a[i].y, a[i].z, a[i].w};
#pragma unroll
        for (int kk = 0; kk < 4; ++kk) {
          acc[i][0] += av[kk] * bb[kk].x;
          acc[i][1] += av[kk] * bb[kk].y;
          acc[i][2] += av[kk] * bb[kk].z;
          acc[i][3] += av[kk] * bb[kk].w;
        }
      }
    }
  }
  int c = c0 + tx * 4;
#pragma unroll
  for (int i = 0; i < 4; ++i) {
    int row = r0 + ty * 4 + i;
    float4 o;
    o.x = fmaxf(acc[i][0] + bias[c + 0], 0.f);
    o.y = fmaxf(acc[i][1] + bias[c + 1], 0.f);
    o.z = fmaxf(acc[i][2] + bias[c + 2], 0.f);
    o.w = fmaxf(acc[i][3] + bias[c + 3], 0.f);
    *(float4*)&H[(size_t)row * IDIM + c] = o;
  }
}

// ---------------------------------------------------------------- GEMM2: z = sum_i h_i@W2_i + b2s + 2x
__global__ __launch_bounds__(256) void gemm2_kernel(
    const float* __restrict__ h, const float* __restrict__ w2,
    const float* __restrict__ b2, const float* __restrict__ uf,
    const float* __restrict__ itf, float* __restrict__ zu, float* __restrict__ zi) {
  int s = blockIdx.z;
  const float* X = s ? itf : uf;
  float* Z = s ? zi : zu;
  int r0 = blockIdx.x * 64, c0 = blockIdx.y * 64;
  __shared__ float As[64][68];
  __shared__ float Bs[64][64];
  int tid = threadIdx.x;
  int lr = tid >> 4, lc = (tid & 15) * 4;
  int tx = tid & 15, ty = tid >> 4;
  float acc[4][4] = {};
  for (int pi = 0; pi < 2; ++pi) {
    int p = s * 2 + pi;
    const float* A = h + (size_t)p * B_C * IDIM;
    const float* Bm = w2 + (size_t)p * IDIM * CDIM;
    for (int k0 = 0; k0 < IDIM; k0 += 64) {
      __syncthreads();
#pragma unroll
      for (int rr = 0; rr < 64; rr += 16) {
        float4 a = *(const float4*)&A[(size_t)(r0 + lr + rr) * IDIM + k0 + lc];
        *(float4*)&As[lr + rr][lc] = a;
        float4 bv = *(const float4*)&Bm[(size_t)(k0 + lr + rr) * CDIM + c0 + lc];
        *(float4*)&Bs[lr + rr][lc] = bv;
      }
      __syncthreads();
#pragma unroll
      for (int k = 0; k < 64; k += 4) {
        float4 a[4], bb[4];
#pragma unroll
        for (int i = 0; i < 4; ++i) a[i] = *(const float4*)&As[ty * 4 + i][k];
#pragma unroll
        for (int kk = 0; kk < 4; ++kk) bb[kk] = *(const float4*)&Bs[k + kk][tx * 4];
#pragma unroll
        for (int i = 0; i < 4; ++i) {
          const float av[4] = {a[i].x, a[i].y, a[i].z, a[i].w};
#pragma unroll
          for (int kk = 0; kk < 4; ++kk) {
            acc[i][0] += av[kk] * bb[kk].x;
            acc[i][1] += av[kk] * bb[kk].y;
            acc[i][2] += av[kk] * bb[kk].z;
            acc[i][3] += av[kk] * bb[kk].w;
          }
        }
      }
    }
  }
  int c = c0 + tx * 4;
  float bs0 = b2[(s * 2) * CDIM + c + 0] + b2[(s * 2 + 1) * CDIM + c + 0];
  float bs1 = b2[(s * 2) * CDIM + c + 1] + b2[(s * 2 + 1) * CDIM + c + 1];
  float bs2 = b2[(s * 2) * CDIM + c + 2] + b2[(s * 2 + 1) * CDIM + c + 2];
  float bs3 = b2[(s * 2) * CDIM + c + 3] + b2[(s * 2 + 1) * CDIM + c + 3];
#pragma unroll
  for (int i = 0; i < 4; ++i) {
    int row = r0 + ty * 4 + i;
    float4 x4 = *(const float4*)&X[(size_t)row * CDIM + c];
    float4 o;
    o.x = acc[i][0] + bs0 + 2.f * x4.x;
    o.y = acc[i][1] + bs1 + 2.f * x4.y;
    o.z = acc[i][2] + bs2 + 2.f * x4.z;
    o.w = acc[i][3] + bs3 + 2.f * x4.w;
    *(float4*)&Z[(size_t)row * CDIM + c] = o;
  }
}

// ---------------------------------------------------------------- final L2 normalize
__global__ __launch_bounds__(64) void norm_kernel(
    const float* __restrict__ zu, const float* __restrict__ zi,
    float* __restrict__ out) {
  int b = blockIdx.x, s = blockIdx.y, t = threadIdx.x;
  const float* z = (s ? zi : zu) + (size_t)b * CDIM;
  float v0 = z[t], v1 = z[t + 64], v2 = z[t + 128];
  float q = v0 * v0 + v1 * v1 + v2 * v2;
#pragma unroll
  for (int off = 32; off; off >>= 1) q += __shfl_down(q, off, 64);
  float n = sqrtf(__shfl(q, 0, 64));
  float inv = 1.f / fmaxf(n, 1e-12f);
  float* o = out + (size_t)s * B_C * CDIM + (size_t)b * CDIM;
  o[t] = v0 * inv;
  o[t + 64] = v1 * inv;
  o[t + 128] = v2 * inv;
}

// ---------------------------------------------------------------- launch
extern "C" void kernel_launch(void* const* d_in, const int* in_sizes, int n_in,
                              void* d_out, int out_size, void* d_ws, size_t ws_size,
                              hipStream_t stream) {
  const float* emb   = (const float*)d_in[0];
  const float* cate  = (const float*)d_in[1];
  const float* avals = (const float*)d_in[2];
  const float* lnw   = (const float*)d_in[3];
  const float* lnb   = (const float*)d_in[4];
  const float* w1    = (const float*)d_in[5];
  const float* b1    = (const float*)d_in[6];
  const float* w2    = (const float*)d_in[7];
  const float* b2    = (const float*)d_in[8];
  const int* arows   = (const int*)d_in[9];
  const int* acols   = (const int*)d_in[10];
  const int* cates_  = (const int*)d_in[11];
  const int* clens   = (const int*)d_in[12];
  const int* users   = (const int*)d_in[13];
  const int* items   = (const int*)d_in[14];
  const int* ihm     = (const int*)d_in[15];
  const int* ihl     = (const int*)d_in[16];
  const int* uhm     = (const int*)d_in[17];
  const int* uhl     = (const int*)d_in[18];
  float* out = (float*)d_out;

  float* W = (float*)d_ws;
  float* e1      = W;                         // 9,600,000 f
  float* e2c     = W + 9600000;               // 6,160,384 f (MAXF*64) -> 15,760,384
  int2*  edges   = (int2*)(W + 15760384);     // 2,400,000 int2 -> 20,560,384
  int*   row_ptr = (int*)(W + 20560384);      // 150,532 i -> 20,710,916
  int*   deg     = (int*)(W + 20710916);      // 150,528 i -> 20,861,444 (deg|flag|cnt one memset)
  int*   flag    = (int*)(W + 20861444);      // 150,528 i -> 21,011,972 (padded for scan)
  int*   cnt     = (int*)(W + 21011972);      // 64 i -> 21,012,036
  int*   list    = (int*)(W + 21012036);      // 96,256 i -> 21,108,292
  int*   bsums   = (int*)(W + 21108292);      // 256 i -> 21,108,548
  int*   bsums2  = (int*)(W + 21108548);      // 256 i -> 21,108,804
  float* uf      = W + 21108804;              // 786,432 f -> 21,895,236
  float* itf     = W + 21895236;              // 786,432 f -> 22,681,668 (90.7 MB)
  // pos aliases e2c (dead until spmm_gather4_masked; csr_fill consumes pos first)
  int*   pos = (int*)e2c;                     // 2,400,000 i (9.6 MB of 24.6 MB)
  // post-GNN reuse:
  float* y  = e1;                             // [4][B][192] = 3,145,728 f
  float* h  = e1 + 3145728;                   // [4][B][384] = 6,291,456 f
  float* zu = e2c;                            // 786,432 f
  float* zi = e2c + 786432;                   // 786,432 f

  // ---- CSR build: rank (atomic, 8 indep/thread) -> scans -> atomic-free fill
  (void)hipMemsetAsync(deg, 0, (150528 + 150528 + 64) * sizeof(int), stream);
  rank_kernel<<<(NNZ_C + 2047) / 2048, 256, 0, stream>>>(arows, deg, pos);
  scan_reduce<<<SCAN_B, 1024, 0, stream>>>(deg, bsums);
  scan_final<<<SCAN_B, 1024, 0, stream>>>(deg, bsums, row_ptr);
  csr_fill<<<(NNZ_C + 2047) / 2048, 256, 0, stream>>>(arows, acols, avals, row_ptr, pos, edges);

  // ---- frontier = seeds + N(seeds); deterministic scan compaction
  mark_kernel<<<(2 * B_C + 255) / 256, 256, 0, stream>>>(users, items, row_ptr, edges, flag);
  scan_reduce<<<SCAN_B, 1024, 0, stream>>>(flag, bsums2);
  compact_scan<<<SCAN_B, 1024, 0, stream>>>(flag, bsums2, list, cnt);

  // ---- GNN: e1 full gather; e2 masked+compacted; e3 fused into seed_finish
  spmm_gather4<<<NN / 16, 256, 0, stream>>>(emb, e1, row_ptr, edges);
  spmm_gather4_masked<<<MAXF / 16, 256, 0, stream>>>(e1, e2c, row_ptr, edges, list, cnt);
  seed_finish<<<(2 * B_C) / 16, 256, 0, stream>>>(emb, e1, e2c, flag, row_ptr,
                                                  edges, users, items, uf, itf);

  // ---- features (cols 64..192 of uf/itf)
  feat_kernel<<<(2 * B_C) / 4, 256, 0, stream>>>(emb, cate, cates_, clens, items,
                                                 ihm, ihl, uhm, uhl, uf, itf);

  // ---- MLP blocks
  ln_kernel<<<dim3(B_C, 4), 64, 0, stream>>>(uf, itf, lnw, lnb, y);
  gemm1_kernel<<<dim3(B_C / 64, IDIM / 64, 4), 256, 0, stream>>>(y, w1, b1, h);
  gemm2_kernel<<<dim3(B_C / 64, CDIM / 64, 2), 256, 0, stream>>>(h, w2, b2, uf, itf, zu, zi);
  norm_kernel<<<dim3(B_C, 2), 64, 0, stream>>>(zu, zi, out);
}